// Round 1
// baseline (460.000 us; speedup 1.0000x reference)
//
#include <hip/hip_runtime.h>
#include <hip/hip_bf16.h>

typedef __attribute__((ext_vector_type(8))) short s16x8;
typedef __attribute__((ext_vector_type(4))) short s16x4;
typedef __attribute__((ext_vector_type(2))) short s16x2;
typedef __attribute__((ext_vector_type(4))) float f32x4;

#define BB 16
#define LL 2048
#define HH 768
#define DD 768
#define MM 8

// d_out layout (float elements)
#define O_LOGITS 0
#define O_BID    128
#define O_LID    256
#define O_AGGL   384
#define O_SCALE  98688
#define O_AGGT   98689

// ws layout (bytes)
#define WTT_OFF  0u            // 768*768 bf16 = 1179648
#define PT_OFF   1179648u      // 32768*768 bf16 = 50331648
#define SC_OFF   51511296u     // 16*8*2048 fp32 = 1048576

__device__ __forceinline__ short f2bf(float x) {
  union { float f; unsigned u; } v; v.f = x;
  unsigned r = v.u + 0x7FFFu + ((v.u >> 16) & 1u);
  return (short)(r >> 16);
}
__device__ __forceinline__ float bf2f(short x) {
  union { unsigned u; float f; } v; v.u = ((unsigned)(unsigned short)x) << 16;
  return v.f;
}

// ---------------------------------------------------------------- Wt -> Wt^T bf16
__global__ void k_wt_transpose(const float* __restrict__ Wt, short* __restrict__ Wtt) {
  __shared__ float tile[64][65];
  int kb = blockIdx.x * 64;
  int nb = blockIdx.y * 64;
  int t = threadIdx.x;
  int c = t & 63;
  int r0 = (t >> 6) * 16;
#pragma unroll
  for (int i = 0; i < 16; ++i)
    tile[r0 + i][c] = Wt[(size_t)(kb + r0 + i) * DD + nb + c];
  __syncthreads();
#pragma unroll
  for (int i = 0; i < 16; ++i)
    Wtt[(size_t)(nb + r0 + i) * HH + kb + c] = f2bf(tile[c][r0 + i]);
}

// ---------------------------------------------------------------- aggregated_labels
// agg = (segment-mean of hs over label tokens) @ Wl + bl   (linearity of projection)
__global__ void k_agg_labels(const float* __restrict__ hs, const float* __restrict__ Wl,
                             const float* __restrict__ bl, const int* __restrict__ lmask,
                             float* __restrict__ out) {
  int b = blockIdx.x >> 3, m = blockIdx.x & 7;
  int t = threadIdx.x;
  int lane = t & 63, w = t >> 6;
  __shared__ float hbar[HH];
  __shared__ int list[LL];
  __shared__ int nlist_s;
  if (w == 0) {  // deterministic compaction of matching token indices
    int base = 0;
    for (int win = 0; win < LL / 64; ++win) {
      int l = win * 64 + lane;
      bool match = (lmask[b * LL + l] == m + 1);
      unsigned long long mk = __ballot(match);
      if (match) {
        int pos = base + (int)__popcll(mk & ((1ull << lane) - 1ull));
        list[pos] = l;
      }
      base += (int)__popcll(mk);
    }
    if (lane == 0) nlist_s = base;
  }
  __syncthreads();
  int n = nlist_s;
  float inv = 1.0f / (float)(n > 1 ? n : 1);
  float a0 = 0.f, a1 = 0.f, a2 = 0.f;
  for (int i = 0; i < n; ++i) {
    const float* r = hs + (size_t)(b * LL + list[i]) * HH;
    a0 += r[t]; a1 += r[t + 256]; a2 += r[t + 512];
  }
  hbar[t] = a0 * inv; hbar[t + 256] = a1 * inv; hbar[t + 512] = a2 * inv;
  __syncthreads();
  float o0 = bl[t], o1 = bl[t + 256], o2 = bl[t + 512];
#pragma unroll 4
  for (int k = 0; k < HH; ++k) {
    float h = hbar[k];
    o0 += h * Wl[(size_t)k * DD + t];
    o1 += h * Wl[(size_t)k * DD + t + 256];
    o2 += h * Wl[(size_t)k * DD + t + 512];
  }
  float* dst = out + O_AGGL + (size_t)(b * MM + m) * DD;
  dst[t] = o0; dst[t + 256] = o1; dst[t + 512] = o2;
}

// ---------------------------------------------------------------- proj_text GEMM (bf16 MFMA)
// C[32768][768] = A(hs fp32, reg-staged->bf16) x Wt_t(bf16, N-major) + bt, stored bf16.
#define BM 128
#define BN 128
#define BK 64
#define NT 12

__global__ __launch_bounds__(256, 2)
void k_gemm_pt(const float* __restrict__ A, const short* __restrict__ Bt,
               const float* __restrict__ bias, short* __restrict__ C) {
  __shared__ short As[2][BM][BK];
  __shared__ short Bs[2][BM][BK];
  int t = threadIdx.x;
  int n0 = blockIdx.x * BN;      // x = N tile (6)  -> consecutive blocks share A panel (L2)
  int m0 = blockIdx.y * BM;      // y = M tile (256)
  int lane = t & 63;
  int w = t >> 6;
  int wm = w >> 1, wn = w & 1;
  int srow = t >> 1;             // 0..127 staging row
  int shalf = t & 1;             // which 32-col half

  f32x4 acc[4][4] = {};

  auto stageA = [&](int buf, int kt) {
    const float4* src = (const float4*)(A + (size_t)(m0 + srow) * HH + kt * BK + shalf * 32);
    float4 v[8];
#pragma unroll
    for (int j = 0; j < 8; ++j) v[j] = src[j];
#pragma unroll
    for (int jj = 0; jj < 4; ++jj) {
      float4 x0 = v[2 * jj], x1 = v[2 * jj + 1];
      s16x8 o;
      o[0] = f2bf(x0.x); o[1] = f2bf(x0.y); o[2] = f2bf(x0.z); o[3] = f2bf(x0.w);
      o[4] = f2bf(x1.x); o[5] = f2bf(x1.y); o[6] = f2bf(x1.z); o[7] = f2bf(x1.w);
      int c16 = shalf * 4 + jj;
      *(s16x8*)&As[buf][srow][((c16 ^ (srow & 7)) * 8)] = o;
    }
  };
  auto stageB = [&](int buf, int kt) {
    const short* src = Bt + (size_t)(n0 + srow) * HH + kt * BK + shalf * 32;
#pragma unroll
    for (int jj = 0; jj < 4; ++jj) {
      s16x8 o = *(const s16x8*)(src + jj * 8);
      int c16 = shalf * 4 + jj;
      *(s16x8*)&Bs[buf][srow][((c16 ^ (srow & 7)) * 8)] = o;
    }
  };
  auto compute = [&](int buf) {
#pragma unroll
    for (int kk = 0; kk < 2; ++kk) {
      s16x8 a[4], bb[4];
#pragma unroll
      for (int i = 0; i < 4; ++i) {
        int row = wm * 64 + i * 16 + (lane & 15);
        int c16 = kk * 4 + (lane >> 4);
        a[i] = *(const s16x8*)&As[buf][row][((c16 ^ (row & 7)) * 8)];
      }
#pragma unroll
      for (int i = 0; i < 4; ++i) {
        int row = wn * 64 + i * 16 + (lane & 15);
        int c16 = kk * 4 + (lane >> 4);
        bb[i] = *(const s16x8*)&Bs[buf][row][((c16 ^ (row & 7)) * 8)];
      }
#pragma unroll
      for (int mi = 0; mi < 4; ++mi)
#pragma unroll
        for (int ni = 0; ni < 4; ++ni)
          acc[mi][ni] = __builtin_amdgcn_mfma_f32_16x16x32_bf16(a[mi], bb[ni], acc[mi][ni], 0, 0, 0);
    }
  };

  stageA(0, 0); stageB(0, 0);
  __syncthreads();
  int buf = 0;
  for (int kt = 0; kt < NT; ++kt) {
    if (kt + 1 < NT) { stageA(buf ^ 1, kt + 1); stageB(buf ^ 1, kt + 1); }
    compute(buf);
    __syncthreads();
    buf ^= 1;
  }

#pragma unroll
  for (int mi = 0; mi < 4; ++mi) {
    int row = m0 + wm * 64 + mi * 16 + ((lane >> 4) * 4);
#pragma unroll
    for (int ni = 0; ni < 4; ++ni) {
      int col = n0 + wn * 64 + ni * 16 + (lane & 15);
      float bv = bias[col];
#pragma unroll
      for (int j = 0; j < 4; ++j)
        C[(size_t)(row + j) * DD + col] = f2bf(acc[mi][ni][j] + bv);
    }
  }
}

// ---------------------------------------------------------------- scores = agg . pt / temp (masked)
__global__ void k_scores(const short* __restrict__ pt, const float* __restrict__ outbuf,
                         const int* __restrict__ lmask, const int* __restrict__ amask,
                         const float* __restrict__ temp_p, float* __restrict__ scores) {
  int chunk = blockIdx.x;  // 16 chunks of 128 tokens
  int b = blockIdx.y;      // 16
  int t = threadIdx.x;
  int w = t >> 6, lane = t & 63;
  __shared__ float agg[MM][HH];
  const float* asrc = outbuf + O_AGGL + (size_t)b * MM * DD;
  for (int i = t; i < MM * HH / 4; i += 256)
    *(float4*)&agg[0][i * 4] = *(const float4*)&asrc[i * 4];
  __syncthreads();
  float inv_temp = 1.0f / fmaxf(fabsf(temp_p[0]), 0.1f);
  for (int i = 0; i < 32; ++i) {
    int l = chunk * 128 + w * 32 + i;
    int is_text = (lmask[b * LL + l] == 0) && (amask[b * LL + l] == 1);
    float acc8[8] = {};
    if (is_text) {
      const short* prow = pt + (size_t)(b * LL + l) * DD;
#pragma unroll
      for (int c = 0; c < 3; ++c) {
        s16x4 pv = *(const s16x4*)&prow[c * 256 + lane * 4];
        float p0 = bf2f(pv[0]), p1 = bf2f(pv[1]), p2 = bf2f(pv[2]), p3 = bf2f(pv[3]);
#pragma unroll
        for (int m = 0; m < 8; ++m) {
          float4 av = *(const float4*)&agg[m][c * 256 + lane * 4];
          acc8[m] += p0 * av.x + p1 * av.y + p2 * av.z + p3 * av.w;
        }
      }
#pragma unroll
      for (int m = 0; m < 8; ++m) {
        float v = acc8[m];
        for (int s = 32; s; s >>= 1) v += __shfl_xor(v, s, 64);
        acc8[m] = v;
      }
    }
    if (lane == 0) {
#pragma unroll
      for (int m = 0; m < 8; ++m)
        scores[(size_t)(b * MM + m) * LL + l] = is_text ? acc8[m] * inv_temp : -1e30f;
    }
  }
}

// ---------------------------------------------------------------- row softmax (in place)
__global__ void k_softmax(float* __restrict__ scores) {
  int row = blockIdx.x;
  float* s = scores + (size_t)row * LL;
  int t = threadIdx.x;
  int w = t >> 6, lane = t & 63;
  float v[8];
  float mx = -1e30f;
#pragma unroll
  for (int i = 0; i < 8; ++i) { v[i] = s[t + 256 * i]; mx = fmaxf(mx, v[i]); }
  for (int sh = 32; sh; sh >>= 1) mx = fmaxf(mx, __shfl_xor(mx, sh, 64));
  __shared__ float wred[4];
  __shared__ float wsum[4];
  if (lane == 0) wred[w] = mx;
  __syncthreads();
  mx = fmaxf(fmaxf(wred[0], wred[1]), fmaxf(wred[2], wred[3]));
  float sum = 0.f;
#pragma unroll
  for (int i = 0; i < 8; ++i) { v[i] = __expf(v[i] - mx); sum += v[i]; }
  for (int sh = 32; sh; sh >>= 1) sum += __shfl_xor(sum, sh, 64);
  if (lane == 0) wsum[w] = sum;
  __syncthreads();
  sum = wsum[0] + wsum[1] + wsum[2] + wsum[3];
  float inv = 1.0f / sum;
#pragma unroll
  for (int i = 0; i < 8; ++i) s[t + 256 * i] = v[i] * inv;
}

// ---------------------------------------------------------------- aggregated_text = attn @ pt
__global__ void k_aggtext(const short* __restrict__ pt, const float* __restrict__ attn,
                          float* __restrict__ out) {
  int dt = blockIdx.x;  // 6 tiles of 128
  int b = blockIdx.y;   // 16
  int t = threadIdx.x;
  int dp = (t & 63) * 2;
  int mg = (t >> 6) * 2;
  int d = dt * 128 + dp;
  __shared__ float at_l[MM][128];
  float acc00 = 0.f, acc01 = 0.f, acc10 = 0.f, acc11 = 0.f;
  for (int lc = 0; lc < 16; ++lc) {
    __syncthreads();
    for (int i = t; i < MM * 128; i += 256) {
      int m = i >> 7, ll = i & 127;
      at_l[m][ll] = attn[(size_t)(b * MM + m) * LL + lc * 128 + ll];
    }
    __syncthreads();
    const short* p = pt + (size_t)(b * LL + lc * 128) * DD + d;
#pragma unroll 4
    for (int ll = 0; ll < 128; ++ll) {
      s16x2 pv = *(const s16x2*)(p + (size_t)ll * DD);
      float p0 = bf2f(pv[0]), p1 = bf2f(pv[1]);
      float a0 = at_l[mg][ll], a1 = at_l[mg + 1][ll];
      acc00 += a0 * p0; acc01 += a0 * p1;
      acc10 += a1 * p0; acc11 += a1 * p1;
    }
  }
  float* dst0 = out + O_AGGT + (size_t)(b * MM + mg) * DD + d;
  float* dst1 = out + O_AGGT + (size_t)(b * MM + mg + 1) * DD + d;
  dst0[0] = acc00; dst0[1] = acc01;
  dst1[0] = acc10; dst1[1] = acc11;
}

// ---------------------------------------------------------------- cosine head + ids + scale
__global__ void k_head(const float* __restrict__ lscale_p, float* __restrict__ out) {
  int row = blockIdx.x;   // 128
  int lane = threadIdx.x; // 64
  const float* at = out + O_AGGT + (size_t)row * DD;
  const float* al = out + O_AGGL + (size_t)row * DD;
  float dot = 0.f, nt = 0.f, nl = 0.f;
  for (int i = lane; i < DD; i += 64) {
    float a = at[i], c = al[i];
    dot += a * c; nt += a * a; nl += c * c;
  }
  for (int s = 32; s; s >>= 1) {
    dot += __shfl_xor(dot, s, 64);
    nt  += __shfl_xor(nt, s, 64);
    nl  += __shfl_xor(nl, s, 64);
  }
  if (lane == 0) {
    float scale = expf(lscale_p[0]);
    float denom = fmaxf(sqrtf(nt), 1e-8f) * fmaxf(sqrtf(nl), 1e-8f);
    out[O_LOGITS + row] = dot / denom * scale;
    out[O_BID + row] = (float)(row >> 3);
    out[O_LID + row] = (float)((row & 7) + 1);
    if (row == 0) out[O_SCALE] = scale;
  }
}

extern "C" void kernel_launch(void* const* d_in, const int* in_sizes, int n_in,
                              void* d_out, int out_size, void* d_ws, size_t ws_size,
                              hipStream_t stream) {
  const float* hs    = (const float*)d_in[0];
  const float* Wt    = (const float*)d_in[1];
  const float* bt    = (const float*)d_in[2];
  const float* Wl    = (const float*)d_in[3];
  const float* bl    = (const float*)d_in[4];
  const float* atemp = (const float*)d_in[5];
  const float* lsc   = (const float*)d_in[6];
  const int*   lmask = (const int*)d_in[7];
  const int*   amask = (const int*)d_in[9];
  float* out = (float*)d_out;
  char* ws = (char*)d_ws;
  short* Wtt    = (short*)(ws + WTT_OFF);
  short* pt     = (short*)(ws + PT_OFF);
  float* scores = (float*)(ws + SC_OFF);

  k_wt_transpose<<<dim3(12, 12), 256, 0, stream>>>(Wt, Wtt);
  k_agg_labels<<<128, 256, 0, stream>>>(hs, Wl, bl, lmask, out);
  k_gemm_pt<<<dim3(6, 256), 256, 0, stream>>>(hs, Wtt, bt, pt);
  k_scores<<<dim3(16, 16), 256, 0, stream>>>(pt, out, lmask, amask, atemp, scores);
  k_softmax<<<128, 256, 0, stream>>>(scores);
  k_aggtext<<<dim3(6, 16), 256, 0, stream>>>(pt, scores, out);
  k_head<<<128, 64, 0, stream>>>(lsc, out);
}

// Round 2
// 299.853 us; speedup vs baseline: 1.5341x; 1.5341x over previous
//
#include <hip/hip_runtime.h>
#include <hip/hip_bf16.h>

typedef __attribute__((ext_vector_type(8))) short s16x8;
typedef __attribute__((ext_vector_type(4))) short s16x4;
typedef __attribute__((ext_vector_type(2))) short s16x2;
typedef __attribute__((ext_vector_type(4))) float f32x4;

#define BB 16
#define LL 2048
#define HH 768
#define DD 768
#define MM 8

// d_out layout (float elements)
#define O_LOGITS 0
#define O_BID    128
#define O_LID    256
#define O_AGGL   384
#define O_SCALE  98688
#define O_AGGT   98689

// ws layout (bytes)
#define WTT_OFF  0u            // 768*768 bf16 = 1179648
#define PT_OFF   1179648u      // 32768*768 bf16 = 50331648
#define SC_OFF   51511296u     // 16*8*2048 fp32 = 1048576
#define PART_OFF 52559872u     // 8*128*768 fp32 = 3145728 (aggtext partials)

__device__ __forceinline__ short f2bf(float x) {
  union { float f; unsigned u; } v; v.f = x;
  unsigned r = v.u + 0x7FFFu + ((v.u >> 16) & 1u);
  return (short)(r >> 16);
}
__device__ __forceinline__ float bf2f(short x) {
  union { unsigned u; float f; } v; v.u = ((unsigned)(unsigned short)x) << 16;
  return v.f;
}

// ---------------------------------------------------------------- Wt -> Wt^T bf16
__global__ void k_wt_transpose(const float* __restrict__ Wt, short* __restrict__ Wtt) {
  __shared__ float tile[64][65];
  int kb = blockIdx.x * 64;
  int nb = blockIdx.y * 64;
  int t = threadIdx.x;
  int c = t & 63;
  int r0 = (t >> 6) * 16;
#pragma unroll
  for (int i = 0; i < 16; ++i)
    tile[r0 + i][c] = Wt[(size_t)(kb + r0 + i) * DD + nb + c];
  __syncthreads();
#pragma unroll
  for (int i = 0; i < 16; ++i)
    Wtt[(size_t)(nb + r0 + i) * HH + kb + c] = f2bf(tile[c][r0 + i]);
}

// ---------------------------------------------------------------- aggregated_labels
// agg = (segment-mean of hs over label tokens) @ Wl + bl   (linearity of projection)
__global__ void k_agg_labels(const float* __restrict__ hs, const float* __restrict__ Wl,
                             const float* __restrict__ bl, const int* __restrict__ lmask,
                             float* __restrict__ out) {
  int b = blockIdx.x >> 3, m = blockIdx.x & 7;
  int t = threadIdx.x;
  int lane = t & 63, w = t >> 6;
  __shared__ float hbar[HH];
  __shared__ int list[LL];
  __shared__ int nlist_s;
  if (w == 0) {  // deterministic compaction of matching token indices
    int base = 0;
    for (int win = 0; win < LL / 64; ++win) {
      int l = win * 64 + lane;
      bool match = (lmask[b * LL + l] == m + 1);
      unsigned long long mk = __ballot(match);
      if (match) {
        int pos = base + (int)__popcll(mk & ((1ull << lane) - 1ull));
        list[pos] = l;
      }
      base += (int)__popcll(mk);
    }
    if (lane == 0) nlist_s = base;
  }
  __syncthreads();
  int n = nlist_s;
  float inv = 1.0f / (float)(n > 1 ? n : 1);
  float a0 = 0.f, a1 = 0.f, a2 = 0.f;
  for (int i = 0; i < n; ++i) {
    const float* r = hs + (size_t)(b * LL + list[i]) * HH;
    a0 += r[t]; a1 += r[t + 256]; a2 += r[t + 512];
  }
  hbar[t] = a0 * inv; hbar[t + 256] = a1 * inv; hbar[t + 512] = a2 * inv;
  __syncthreads();
  float o0 = bl[t], o1 = bl[t + 256], o2 = bl[t + 512];
#pragma unroll 4
  for (int k = 0; k < HH; ++k) {
    float h = hbar[k];
    o0 += h * Wl[(size_t)k * DD + t];
    o1 += h * Wl[(size_t)k * DD + t + 256];
    o2 += h * Wl[(size_t)k * DD + t + 512];
  }
  float* dst = out + O_AGGL + (size_t)(b * MM + m) * DD;
  dst[t] = o0; dst[t + 256] = o1; dst[t + 512] = o2;
}

// ---------------------------------------------------------------- proj_text GEMM (bf16 MFMA)
// C[32768][768] = A(hs fp32, reg-staged->bf16) x Wt_t(bf16, N-major) + bt, stored bf16.
#define BM 128
#define BN 128
#define BK 64
#define NT 12

__global__ __launch_bounds__(256, 2)
void k_gemm_pt(const float* __restrict__ A, const short* __restrict__ Bt,
               const float* __restrict__ bias, short* __restrict__ C) {
  __shared__ short As[2][BM][BK];
  __shared__ short Bs[2][BM][BK];
  int t = threadIdx.x;
  int n0 = blockIdx.x * BN;      // x = N tile (6)  -> consecutive blocks share A panel (L2)
  int m0 = blockIdx.y * BM;      // y = M tile (256)
  int lane = t & 63;
  int w = t >> 6;
  int wm = w >> 1, wn = w & 1;
  int srow = t >> 1;             // 0..127 staging row
  int shalf = t & 1;             // which 32-col half

  f32x4 acc[4][4] = {};

  auto stageA = [&](int buf, int kt) {
    const float4* src = (const float4*)(A + (size_t)(m0 + srow) * HH + kt * BK + shalf * 32);
    float4 v[8];
#pragma unroll
    for (int j = 0; j < 8; ++j) v[j] = src[j];
#pragma unroll
    for (int jj = 0; jj < 4; ++jj) {
      float4 x0 = v[2 * jj], x1 = v[2 * jj + 1];
      s16x8 o;
      o[0] = f2bf(x0.x); o[1] = f2bf(x0.y); o[2] = f2bf(x0.z); o[3] = f2bf(x0.w);
      o[4] = f2bf(x1.x); o[5] = f2bf(x1.y); o[6] = f2bf(x1.z); o[7] = f2bf(x1.w);
      int c16 = shalf * 4 + jj;
      *(s16x8*)&As[buf][srow][((c16 ^ (srow & 7)) * 8)] = o;
    }
  };
  auto stageB = [&](int buf, int kt) {
    const short* src = Bt + (size_t)(n0 + srow) * HH + kt * BK + shalf * 32;
#pragma unroll
    for (int jj = 0; jj < 4; ++jj) {
      s16x8 o = *(const s16x8*)(src + jj * 8);
      int c16 = shalf * 4 + jj;
      *(s16x8*)&Bs[buf][srow][((c16 ^ (srow & 7)) * 8)] = o;
    }
  };
  auto compute = [&](int buf) {
#pragma unroll
    for (int kk = 0; kk < 2; ++kk) {
      s16x8 a[4], bb[4];
#pragma unroll
      for (int i = 0; i < 4; ++i) {
        int row = wm * 64 + i * 16 + (lane & 15);
        int c16 = kk * 4 + (lane >> 4);
        a[i] = *(const s16x8*)&As[buf][row][((c16 ^ (row & 7)) * 8)];
      }
#pragma unroll
      for (int i = 0; i < 4; ++i) {
        int row = wn * 64 + i * 16 + (lane & 15);
        int c16 = kk * 4 + (lane >> 4);
        bb[i] = *(const s16x8*)&Bs[buf][row][((c16 ^ (row & 7)) * 8)];
      }
#pragma unroll
      for (int mi = 0; mi < 4; ++mi)
#pragma unroll
        for (int ni = 0; ni < 4; ++ni)
          acc[mi][ni] = __builtin_amdgcn_mfma_f32_16x16x32_bf16(a[mi], bb[ni], acc[mi][ni], 0, 0, 0);
    }
  };

  stageA(0, 0); stageB(0, 0);
  __syncthreads();
  int buf = 0;
  for (int kt = 0; kt < NT; ++kt) {
    if (kt + 1 < NT) { stageA(buf ^ 1, kt + 1); stageB(buf ^ 1, kt + 1); }
    compute(buf);
    __syncthreads();
    buf ^= 1;
  }

#pragma unroll
  for (int mi = 0; mi < 4; ++mi) {
    int row = m0 + wm * 64 + mi * 16 + ((lane >> 4) * 4);
#pragma unroll
    for (int ni = 0; ni < 4; ++ni) {
      int col = n0 + wn * 64 + ni * 16 + (lane & 15);
      float bv = bias[col];
#pragma unroll
      for (int j = 0; j < 4; ++j)
        C[(size_t)(row + j) * DD + col] = f2bf(acc[mi][ni][j] + bv);
    }
  }
}

// ---------------------------------------------------------------- scores = agg . pt / temp (masked)
__global__ void k_scores(const short* __restrict__ pt, const float* __restrict__ outbuf,
                         const int* __restrict__ lmask, const int* __restrict__ amask,
                         const float* __restrict__ temp_p, float* __restrict__ scores) {
  int chunk = blockIdx.x;  // 16 chunks of 128 tokens
  int b = blockIdx.y;      // 16
  int t = threadIdx.x;
  int w = t >> 6, lane = t & 63;
  __shared__ float agg[MM][HH];
  const float* asrc = outbuf + O_AGGL + (size_t)b * MM * DD;
  for (int i = t; i < MM * HH / 4; i += 256)
    *(float4*)&agg[0][i * 4] = *(const float4*)&asrc[i * 4];
  __syncthreads();
  float inv_temp = 1.0f / fmaxf(fabsf(temp_p[0]), 0.1f);
  for (int i = 0; i < 32; ++i) {
    int l = chunk * 128 + w * 32 + i;
    int is_text = (lmask[b * LL + l] == 0) && (amask[b * LL + l] == 1);
    float acc8[8] = {};
    if (is_text) {
      const short* prow = pt + (size_t)(b * LL + l) * DD;
#pragma unroll
      for (int c = 0; c < 3; ++c) {
        s16x4 pv = *(const s16x4*)&prow[c * 256 + lane * 4];
        float p0 = bf2f(pv[0]), p1 = bf2f(pv[1]), p2 = bf2f(pv[2]), p3 = bf2f(pv[3]);
#pragma unroll
        for (int m = 0; m < 8; ++m) {
          float4 av = *(const float4*)&agg[m][c * 256 + lane * 4];
          acc8[m] += p0 * av.x + p1 * av.y + p2 * av.z + p3 * av.w;
        }
      }
#pragma unroll
      for (int m = 0; m < 8; ++m) {
        float v = acc8[m];
        for (int s = 32; s; s >>= 1) v += __shfl_xor(v, s, 64);
        acc8[m] = v;
      }
    }
    if (lane == 0) {
#pragma unroll
      for (int m = 0; m < 8; ++m)
        scores[(size_t)(b * MM + m) * LL + l] = is_text ? acc8[m] * inv_temp : -1e30f;
    }
  }
}

// ---------------------------------------------------------------- row softmax (in place)
__global__ void k_softmax(float* __restrict__ scores) {
  int row = blockIdx.x;
  float* s = scores + (size_t)row * LL;
  int t = threadIdx.x;
  int w = t >> 6, lane = t & 63;
  float v[8];
  float mx = -1e30f;
#pragma unroll
  for (int i = 0; i < 8; ++i) { v[i] = s[t + 256 * i]; mx = fmaxf(mx, v[i]); }
  for (int sh = 32; sh; sh >>= 1) mx = fmaxf(mx, __shfl_xor(mx, sh, 64));
  __shared__ float wred[4];
  __shared__ float wsum[4];
  if (lane == 0) wred[w] = mx;
  __syncthreads();
  mx = fmaxf(fmaxf(wred[0], wred[1]), fmaxf(wred[2], wred[3]));
  float sum = 0.f;
#pragma unroll
  for (int i = 0; i < 8; ++i) { v[i] = __expf(v[i] - mx); sum += v[i]; }
  for (int sh = 32; sh; sh >>= 1) sum += __shfl_xor(sum, sh, 64);
  if (lane == 0) wsum[w] = sum;
  __syncthreads();
  sum = wsum[0] + wsum[1] + wsum[2] + wsum[3];
  float inv = 1.0f / sum;
#pragma unroll
  for (int i = 0; i < 8; ++i) s[t + 256 * i] = v[i] * inv;
}

// ---------------------------------------------------------------- aggregated_text partials
// part[lc][b][m][d] = sum over 256-token chunk lc of attn * pt   (8 chunks)
__global__ void k_aggtext_part(const short* __restrict__ pt, const float* __restrict__ attn,
                               float* __restrict__ part) {
  int lc = blockIdx.x;   // 8 chunks of 256 tokens
  int dt = blockIdx.y;   // 6 tiles of 128 cols
  int b  = blockIdx.z;   // 16
  int t = threadIdx.x;
  int m  = t >> 5;       // 0..7
  int c4 = t & 31;       // col quad within 128-col tile
  __shared__ float at_l[MM][256];
  for (int i = t; i < MM * 256; i += 256) {
    int mm = i >> 8, ll = i & 255;
    at_l[mm][ll] = attn[(size_t)(b * MM + mm) * LL + lc * 256 + ll];
  }
  __syncthreads();
  float ax = 0.f, ay = 0.f, az = 0.f, aw = 0.f;
  const short* p = pt + (size_t)(b * LL + lc * 256) * DD + dt * 128 + c4 * 4;
#pragma unroll 4
  for (int ll = 0; ll < 256; ++ll) {
    s16x4 pv = *(const s16x4*)(p + (size_t)ll * DD);
    float a = at_l[m][ll];
    ax += a * bf2f(pv[0]); ay += a * bf2f(pv[1]);
    az += a * bf2f(pv[2]); aw += a * bf2f(pv[3]);
  }
  float* dst = part + ((size_t)(lc * BB + b) * MM + m) * DD + dt * 128 + c4 * 4;
  float4 acc = {ax, ay, az, aw};
  *(float4*)dst = acc;
}

// ---------------------------------------------------------------- reduce partials + cosine head
__global__ void k_head(const float* __restrict__ part, const float* __restrict__ lscale_p,
                       float* __restrict__ out) {
  int row = blockIdx.x;   // 128 (= b*8 + m)
  int lane = threadIdx.x; // 64
  int b = row >> 3, m = row & 7;
  const float* al = out + O_AGGL + (size_t)row * DD;
  float* at_out = out + O_AGGT + (size_t)row * DD;
  float dot = 0.f, nt = 0.f, nl = 0.f;
  for (int i = lane; i < DD; i += 64) {
    float a = 0.f;
#pragma unroll
    for (int lc = 0; lc < 8; ++lc)
      a += part[((size_t)(lc * BB + b) * MM + m) * DD + i];
    float c = al[i];
    at_out[i] = a;
    dot += a * c; nt += a * a; nl += c * c;
  }
  for (int s = 32; s; s >>= 1) {
    dot += __shfl_xor(dot, s, 64);
    nt  += __shfl_xor(nt, s, 64);
    nl  += __shfl_xor(nl, s, 64);
  }
  if (lane == 0) {
    float scale = expf(lscale_p[0]);
    float denom = fmaxf(sqrtf(nt), 1e-8f) * fmaxf(sqrtf(nl), 1e-8f);
    out[O_LOGITS + row] = dot / denom * scale;
    out[O_BID + row] = (float)(row >> 3);
    out[O_LID + row] = (float)((row & 7) + 1);
    if (row == 0) out[O_SCALE] = scale;
  }
}

extern "C" void kernel_launch(void* const* d_in, const int* in_sizes, int n_in,
                              void* d_out, int out_size, void* d_ws, size_t ws_size,
                              hipStream_t stream) {
  const float* hs    = (const float*)d_in[0];
  const float* Wt    = (const float*)d_in[1];
  const float* bt    = (const float*)d_in[2];
  const float* Wl    = (const float*)d_in[3];
  const float* bl    = (const float*)d_in[4];
  const float* atemp = (const float*)d_in[5];
  const float* lsc   = (const float*)d_in[6];
  const int*   lmask = (const int*)d_in[7];
  const int*   amask = (const int*)d_in[9];
  float* out = (float*)d_out;
  char* ws = (char*)d_ws;
  short* Wtt    = (short*)(ws + WTT_OFF);
  short* pt     = (short*)(ws + PT_OFF);
  float* scores = (float*)(ws + SC_OFF);
  float* part   = (float*)(ws + PART_OFF);

  k_wt_transpose<<<dim3(12, 12), 256, 0, stream>>>(Wt, Wtt);
  k_agg_labels<<<128, 256, 0, stream>>>(hs, Wl, bl, lmask, out);
  k_gemm_pt<<<dim3(6, 256), 256, 0, stream>>>(hs, Wtt, bt, pt);
  k_scores<<<dim3(16, 16), 256, 0, stream>>>(pt, out, lmask, amask, atemp, scores);
  k_softmax<<<128, 256, 0, stream>>>(scores);
  k_aggtext_part<<<dim3(8, 6, 16), 256, 0, stream>>>(pt, scores, part);
  k_head<<<128, 64, 0, stream>>>(part, lsc, out);
}

// Round 3
// 273.591 us; speedup vs baseline: 1.6813x; 1.0960x over previous
//
#include <hip/hip_runtime.h>
#include <hip/hip_bf16.h>

typedef __attribute__((ext_vector_type(8))) short s16x8;
typedef __attribute__((ext_vector_type(4))) short s16x4;
typedef __attribute__((ext_vector_type(2))) short s16x2;
typedef __attribute__((ext_vector_type(4))) float f32x4;

#define BB 16
#define LL 2048
#define HH 768
#define DD 768
#define MM 8

// d_out layout (float elements)
#define O_LOGITS 0
#define O_BID    128
#define O_LID    256
#define O_AGGL   384
#define O_SCALE  98688
#define O_AGGT   98689

// ws layout (bytes)
#define WTT_OFF  0u            // 768*768 bf16 = 1179648
#define PT_OFF   1179648u      // 32768*768 bf16 = 50331648
#define SC_OFF   51511296u     // 16*8*2048 fp32 = 1048576
#define PART_OFF 52559872u     // 8*128*768 fp32 = 3145728 (aggtext partials)

__device__ __forceinline__ short f2bf(float x) {
  union { float f; unsigned u; } v; v.f = x;
  unsigned r = v.u + 0x7FFFu + ((v.u >> 16) & 1u);
  return (short)(r >> 16);
}
__device__ __forceinline__ float bf2f(short x) {
  union { unsigned u; float f; } v; v.u = ((unsigned)(unsigned short)x) << 16;
  return v.f;
}

// async global->LDS, 16B per lane; LDS dest must be wave-uniform base (HW adds lane*16)
#define GLOAD_LDS16(gp, lp) __builtin_amdgcn_global_load_lds( \
    (const __attribute__((address_space(1))) unsigned int*)(gp), \
    (__attribute__((address_space(3))) unsigned int*)(lp), 16, 0, 0)

// ---------------------------------------------------------------- Wt -> Wt^T bf16
__global__ void k_wt_transpose(const float* __restrict__ Wt, short* __restrict__ Wtt) {
  __shared__ float tile[64][65];
  int kb = blockIdx.x * 64;
  int nb = blockIdx.y * 64;
  int t = threadIdx.x;
  int c = t & 63;
  int r0 = (t >> 6) * 16;
#pragma unroll
  for (int i = 0; i < 16; ++i)
    tile[r0 + i][c] = Wt[(size_t)(kb + r0 + i) * DD + nb + c];
  __syncthreads();
#pragma unroll
  for (int i = 0; i < 16; ++i)
    Wtt[(size_t)(nb + r0 + i) * HH + kb + c] = f2bf(tile[c][r0 + i]);
}

// ---------------------------------------------------------------- aggregated_labels
__global__ void k_agg_labels(const float* __restrict__ hs, const float* __restrict__ Wl,
                             const float* __restrict__ bl, const int* __restrict__ lmask,
                             float* __restrict__ out) {
  int b = blockIdx.x >> 3, m = blockIdx.x & 7;
  int t = threadIdx.x;
  int lane = t & 63, w = t >> 6;
  __shared__ float hbar[HH];
  __shared__ int list[LL];
  __shared__ int nlist_s;
  if (w == 0) {
    int base = 0;
    for (int win = 0; win < LL / 64; ++win) {
      int l = win * 64 + lane;
      bool match = (lmask[b * LL + l] == m + 1);
      unsigned long long mk = __ballot(match);
      if (match) {
        int pos = base + (int)__popcll(mk & ((1ull << lane) - 1ull));
        list[pos] = l;
      }
      base += (int)__popcll(mk);
    }
    if (lane == 0) nlist_s = base;
  }
  __syncthreads();
  int n = nlist_s;
  float inv = 1.0f / (float)(n > 1 ? n : 1);
  float a0 = 0.f, a1 = 0.f, a2 = 0.f;
  for (int i = 0; i < n; ++i) {
    const float* r = hs + (size_t)(b * LL + list[i]) * HH;
    a0 += r[t]; a1 += r[t + 256]; a2 += r[t + 512];
  }
  hbar[t] = a0 * inv; hbar[t + 256] = a1 * inv; hbar[t + 512] = a2 * inv;
  __syncthreads();
  float o0 = bl[t], o1 = bl[t + 256], o2 = bl[t + 512];
#pragma unroll 4
  for (int k = 0; k < HH; ++k) {
    float h = hbar[k];
    o0 += h * Wl[(size_t)k * DD + t];
    o1 += h * Wl[(size_t)k * DD + t + 256];
    o2 += h * Wl[(size_t)k * DD + t + 512];
  }
  float* dst = out + O_AGGL + (size_t)(b * MM + m) * DD;
  dst[t] = o0; dst[t + 256] = o1; dst[t + 512] = o2;
}

// ---------------------------------------------------------------- proj_text GEMM
// m97-style: global_load_lds staging (A fp32 in LDS, cvt_pk->bf16 at frag read;
// B bf16), single LDS buffer, 2 barriers/K-step, 3 blocks/CU, XCD-affinity remap.
#define Bb_M 128
#define Bb_N 128
#define Bb_K 64
#define NTK 12

__global__ __launch_bounds__(256, 3)
void k_gemm_pt(const float* __restrict__ A, const short* __restrict__ Bt,
               const float* __restrict__ bias, short* __restrict__ C) {
  __shared__ float As[Bb_M][Bb_K];   // 32 KB
  __shared__ short Bs[Bb_M][Bb_K];   // 16 KB
  int t = threadIdx.x;
  int lane = t & 63;
  int w = t >> 6;
  int wm = w >> 1, wn = w & 1;

  // XCD-affinity remap: 6 N-tiles of one M-panel land on the same XCD (A L2 reuse)
  int id = blockIdx.x;           // 1536
  int xcd = id & 7, q = id >> 3; // q 0..191
  int m0 = ((q / 6) * 8 + xcd) * Bb_M;
  int n0 = (q % 6) * Bb_N;

  f32x4 acc[4][4] = {};

  auto stage = [&](int kt) {
    const float* Ag = A + (size_t)m0 * HH + kt * Bb_K;
    const short* Bg = Bt + (size_t)n0 * HH + kt * Bb_K;
#pragma unroll
    for (int i = 0; i < 8; ++i) {   // A: 128 rows x 16 chunks = 2048 slots
      int slot = i * 256 + w * 64 + lane;
      int row = slot >> 4, c = slot & 15;
      GLOAD_LDS16(Ag + (size_t)row * HH + c * 4,
                  (char*)As + (size_t)(i * 256 + w * 64) * 16);
    }
#pragma unroll
    for (int i = 0; i < 4; ++i) {   // B: 128 rows x 8 chunks = 1024 slots
      int slot = i * 256 + w * 64 + lane;
      int row = slot >> 3, c = slot & 7;
      GLOAD_LDS16(Bg + (size_t)row * HH + c * 8,
                  (char*)Bs + (size_t)(i * 256 + w * 64) * 16);
    }
  };

  auto cvt8 = [&](float4 x0, float4 x1) -> s16x8 {
    union { unsigned u[4]; s16x8 v; } r;
    asm("v_cvt_pk_bf16_f32 %0, %1, %2" : "=v"(r.u[0]) : "v"(x0.x), "v"(x0.y));
    asm("v_cvt_pk_bf16_f32 %0, %1, %2" : "=v"(r.u[1]) : "v"(x0.z), "v"(x0.w));
    asm("v_cvt_pk_bf16_f32 %0, %1, %2" : "=v"(r.u[2]) : "v"(x1.x), "v"(x1.y));
    asm("v_cvt_pk_bf16_f32 %0, %1, %2" : "=v"(r.u[3]) : "v"(x1.z), "v"(x1.w));
    return r.v;
  };

  auto compute = [&]() {
#pragma unroll
    for (int kk = 0; kk < 2; ++kk) {
      s16x8 a[4], bb[4];
#pragma unroll
      for (int i = 0; i < 4; ++i) {
        int row = wm * 64 + i * 16 + (lane & 15);
        int k0 = kk * 32 + (lane >> 4) * 8;
        float4 x0 = *(const float4*)&As[row][k0];
        float4 x1 = *(const float4*)&As[row][k0 + 4];
        a[i] = cvt8(x0, x1);
      }
#pragma unroll
      for (int i = 0; i < 4; ++i) {
        int row = wn * 64 + i * 16 + (lane & 15);
        bb[i] = *(const s16x8*)&Bs[row][kk * 32 + (lane >> 4) * 8];
      }
#pragma unroll
      for (int mi = 0; mi < 4; ++mi)
#pragma unroll
        for (int ni = 0; ni < 4; ++ni)
          acc[mi][ni] = __builtin_amdgcn_mfma_f32_16x16x32_bf16(a[mi], bb[ni], acc[mi][ni], 0, 0, 0);
    }
  };

  for (int kt = 0; kt < NTK; ++kt) {
    stage(kt);
    __syncthreads();   // compiler emits vmcnt(0) drain before barrier (m97 regime)
    compute();
    __syncthreads();
  }

#pragma unroll
  for (int mi = 0; mi < 4; ++mi) {
    int row = m0 + wm * 64 + mi * 16 + ((lane >> 4) * 4);
#pragma unroll
    for (int ni = 0; ni < 4; ++ni) {
      int col = n0 + wn * 64 + ni * 16 + (lane & 15);
      float bv = bias[col];
#pragma unroll
      for (int j = 0; j < 4; ++j)
        C[(size_t)(row + j) * DD + col] = f2bf(acc[mi][ni][j] + bv);
    }
  }
}

// ---------------------------------------------------------------- scores = agg . pt / temp (masked)
__global__ void k_scores(const short* __restrict__ pt, const float* __restrict__ outbuf,
                         const int* __restrict__ lmask, const int* __restrict__ amask,
                         const float* __restrict__ temp_p, float* __restrict__ scores) {
  int chunk = blockIdx.x;
  int b = blockIdx.y;
  int t = threadIdx.x;
  int w = t >> 6, lane = t & 63;
  __shared__ float agg[MM][HH];
  const float* asrc = outbuf + O_AGGL + (size_t)b * MM * DD;
  for (int i = t; i < MM * HH / 4; i += 256)
    *(float4*)&agg[0][i * 4] = *(const float4*)&asrc[i * 4];
  __syncthreads();
  float inv_temp = 1.0f / fmaxf(fabsf(temp_p[0]), 0.1f);
  for (int i = 0; i < 32; ++i) {
    int l = chunk * 128 + w * 32 + i;
    int is_text = (lmask[b * LL + l] == 0) && (amask[b * LL + l] == 1);
    float acc8[8] = {};
    if (is_text) {
      const short* prow = pt + (size_t)(b * LL + l) * DD;
#pragma unroll
      for (int c = 0; c < 3; ++c) {
        s16x4 pv = *(const s16x4*)&prow[c * 256 + lane * 4];
        float p0 = bf2f(pv[0]), p1 = bf2f(pv[1]), p2 = bf2f(pv[2]), p3 = bf2f(pv[3]);
#pragma unroll
        for (int m = 0; m < 8; ++m) {
          float4 av = *(const float4*)&agg[m][c * 256 + lane * 4];
          acc8[m] += p0 * av.x + p1 * av.y + p2 * av.z + p3 * av.w;
        }
      }
#pragma unroll
      for (int m = 0; m < 8; ++m) {
        float v = acc8[m];
        for (int s = 32; s; s >>= 1) v += __shfl_xor(v, s, 64);
        acc8[m] = v;
      }
    }
    if (lane == 0) {
#pragma unroll
      for (int m = 0; m < 8; ++m)
        scores[(size_t)(b * MM + m) * LL + l] = is_text ? acc8[m] * inv_temp : -1e30f;
    }
  }
}

// ---------------------------------------------------------------- row softmax (in place)
__global__ void k_softmax(float* __restrict__ scores) {
  int row = blockIdx.x;
  float* s = scores + (size_t)row * LL;
  int t = threadIdx.x;
  int w = t >> 6, lane = t & 63;
  float v[8];
  float mx = -1e30f;
#pragma unroll
  for (int i = 0; i < 8; ++i) { v[i] = s[t + 256 * i]; mx = fmaxf(mx, v[i]); }
  for (int sh = 32; sh; sh >>= 1) mx = fmaxf(mx, __shfl_xor(mx, sh, 64));
  __shared__ float wred[4];
  __shared__ float wsum[4];
  if (lane == 0) wred[w] = mx;
  __syncthreads();
  mx = fmaxf(fmaxf(wred[0], wred[1]), fmaxf(wred[2], wred[3]));
  float sum = 0.f;
#pragma unroll
  for (int i = 0; i < 8; ++i) { v[i] = __expf(v[i] - mx); sum += v[i]; }
  for (int sh = 32; sh; sh >>= 1) sum += __shfl_xor(sum, sh, 64);
  if (lane == 0) wsum[w] = sum;
  __syncthreads();
  sum = wsum[0] + wsum[1] + wsum[2] + wsum[3];
  float inv = 1.0f / sum;
#pragma unroll
  for (int i = 0; i < 8; ++i) s[t + 256 * i] = v[i] * inv;
}

// ---------------------------------------------------------------- aggregated_text partials
__global__ void k_aggtext_part(const short* __restrict__ pt, const float* __restrict__ attn,
                               float* __restrict__ part) {
  int lc = blockIdx.x;
  int dt = blockIdx.y;
  int b  = blockIdx.z;
  int t = threadIdx.x;
  int m  = t >> 5;
  int c4 = t & 31;
  __shared__ float at_l[MM][256];
  for (int i = t; i < MM * 256; i += 256) {
    int mm = i >> 8, ll = i & 255;
    at_l[mm][ll] = attn[(size_t)(b * MM + mm) * LL + lc * 256 + ll];
  }
  __syncthreads();
  float ax = 0.f, ay = 0.f, az = 0.f, aw = 0.f;
  const short* p = pt + (size_t)(b * LL + lc * 256) * DD + dt * 128 + c4 * 4;
#pragma unroll 4
  for (int ll = 0; ll < 256; ++ll) {
    s16x4 pv = *(const s16x4*)(p + (size_t)ll * DD);
    float a = at_l[m][ll];
    ax += a * bf2f(pv[0]); ay += a * bf2f(pv[1]);
    az += a * bf2f(pv[2]); aw += a * bf2f(pv[3]);
  }
  float* dst = part + ((size_t)(lc * BB + b) * MM + m) * DD + dt * 128 + c4 * 4;
  float4 acc = {ax, ay, az, aw};
  *(float4*)dst = acc;
}

// ---------------------------------------------------------------- reduce partials + cosine head
__global__ void k_head(const float* __restrict__ part, const float* __restrict__ lscale_p,
                       float* __restrict__ out) {
  int row = blockIdx.x;
  int lane = threadIdx.x;
  int b = row >> 3, m = row & 7;
  const float* al = out + O_AGGL + (size_t)row * DD;
  float* at_out = out + O_AGGT + (size_t)row * DD;
  float dot = 0.f, nt = 0.f, nl = 0.f;
  for (int i = lane; i < DD; i += 64) {
    float a = 0.f;
#pragma unroll
    for (int lc = 0; lc < 8; ++lc)
      a += part[((size_t)(lc * BB + b) * MM + m) * DD + i];
    float c = al[i];
    at_out[i] = a;
    dot += a * c; nt += a * a; nl += c * c;
  }
  for (int s = 32; s; s >>= 1) {
    dot += __shfl_xor(dot, s, 64);
    nt  += __shfl_xor(nt, s, 64);
    nl  += __shfl_xor(nl, s, 64);
  }
  if (lane == 0) {
    float scale = expf(lscale_p[0]);
    float denom = fmaxf(sqrtf(nt), 1e-8f) * fmaxf(sqrtf(nl), 1e-8f);
    out[O_LOGITS + row] = dot / denom * scale;
    out[O_BID + row] = (float)(row >> 3);
    out[O_LID + row] = (float)((row & 7) + 1);
    if (row == 0) out[O_SCALE] = scale;
  }
}

extern "C" void kernel_launch(void* const* d_in, const int* in_sizes, int n_in,
                              void* d_out, int out_size, void* d_ws, size_t ws_size,
                              hipStream_t stream) {
  const float* hs    = (const float*)d_in[0];
  const float* Wt    = (const float*)d_in[1];
  const float* bt    = (const float*)d_in[2];
  const float* Wl    = (const float*)d_in[3];
  const float* bl    = (const float*)d_in[4];
  const float* atemp = (const float*)d_in[5];
  const float* lsc   = (const float*)d_in[6];
  const int*   lmask = (const int*)d_in[7];
  const int*   amask = (const int*)d_in[9];
  float* out = (float*)d_out;
  char* ws = (char*)d_ws;
  short* Wtt    = (short*)(ws + WTT_OFF);
  short* pt     = (short*)(ws + PT_OFF);
  float* scores = (float*)(ws + SC_OFF);
  float* part   = (float*)(ws + PART_OFF);

  k_wt_transpose<<<dim3(12, 12), 256, 0, stream>>>(Wt, Wtt);
  k_agg_labels<<<128, 256, 0, stream>>>(hs, Wl, bl, lmask, out);
  k_gemm_pt<<<1536, 256, 0, stream>>>(hs, Wtt, bt, pt);
  k_scores<<<dim3(16, 16), 256, 0, stream>>>(pt, out, lmask, amask, atemp, scores);
  k_softmax<<<128, 256, 0, stream>>>(scores);
  k_aggtext_part<<<dim3(8, 6, 16), 256, 0, stream>>>(pt, scores, part);
  k_head<<<128, 64, 0, stream>>>(part, lsc, out);
}

// Round 4
// 236.866 us; speedup vs baseline: 1.9420x; 1.1550x over previous
//
#include <hip/hip_runtime.h>
#include <hip/hip_bf16.h>

typedef __attribute__((ext_vector_type(8))) short s16x8;
typedef __attribute__((ext_vector_type(4))) short s16x4;
typedef __attribute__((ext_vector_type(2))) short s16x2;
typedef __attribute__((ext_vector_type(4))) float f32x4;

#define BB 16
#define LL 2048
#define HH 768
#define DD 768
#define MM 8

// d_out layout (float elements)
#define O_LOGITS 0
#define O_BID    128
#define O_LID    256
#define O_AGGL   384
#define O_SCALE  98688
#define O_AGGT   98689

// ws layout (bytes)
#define WTT_OFF  0u            // 768*768 bf16 = 1179648
#define PT_OFF   1179648u      // 32768*768 bf16 = 50331648
#define SC_OFF   51511296u     // 16*8*2048 fp32 = 1048576
#define PART_OFF 52559872u     // 8*128*768 fp32 = 3145728
#define WLT_OFF  55705600u     // 768*768 bf16 = 1179648
#define HBAR_OFF 56885248u     // 128*768 fp32 = 393216

__device__ __forceinline__ short f2bf(float x) {
  union { float f; unsigned u; } v; v.f = x;
  unsigned r = v.u + 0x7FFFu + ((v.u >> 16) & 1u);
  return (short)(r >> 16);
}
__device__ __forceinline__ float bf2f(short x) {
  union { unsigned u; float f; } v; v.u = ((unsigned)(unsigned short)x) << 16;
  return v.f;
}

// async global->LDS, 16B per lane; LDS dest is wave-uniform base (HW adds lane*16)
#define GLOAD_LDS16(gp, lp) __builtin_amdgcn_global_load_lds( \
    (const __attribute__((address_space(1))) unsigned int*)(gp), \
    (__attribute__((address_space(3))) unsigned int*)(lp), 16, 0, 0)

// ---------------------------------------------------------------- W -> W^T bf16 (Wt and Wl)
__global__ void k_wt_transpose(const float* __restrict__ Wt, const float* __restrict__ Wl,
                               short* __restrict__ Wtt, short* __restrict__ Wlt) {
  __shared__ float tile[64][65];
  const float* src = blockIdx.z ? Wl : Wt;
  short* dst = blockIdx.z ? Wlt : Wtt;
  int kb = blockIdx.x * 64;
  int nb = blockIdx.y * 64;
  int t = threadIdx.x;
  int c = t & 63;
  int r0 = (t >> 6) * 16;
#pragma unroll
  for (int i = 0; i < 16; ++i)
    tile[r0 + i][c] = src[(size_t)(kb + r0 + i) * DD + nb + c];
  __syncthreads();
#pragma unroll
  for (int i = 0; i < 16; ++i)
    dst[(size_t)(nb + r0 + i) * HH + kb + c] = f2bf(tile[c][r0 + i]);
}

// ---------------------------------------------------------------- hbar = segment-mean of hs
__global__ void k_hbar(const float* __restrict__ hs, const int* __restrict__ lmask,
                       float* __restrict__ hbar) {
  int b = blockIdx.x >> 3, m = blockIdx.x & 7;
  int t = threadIdx.x;
  int lane = t & 63, w = t >> 6;
  __shared__ int list[LL];
  __shared__ int nlist_s;
  if (w == 0) {  // deterministic compaction of matching token indices
    int base = 0;
    for (int win = 0; win < LL / 64; ++win) {
      int l = win * 64 + lane;
      bool match = (lmask[b * LL + l] == m + 1);
      unsigned long long mk = __ballot(match);
      if (match) {
        int pos = base + (int)__popcll(mk & ((1ull << lane) - 1ull));
        list[pos] = l;
      }
      base += (int)__popcll(mk);
    }
    if (lane == 0) nlist_s = base;
  }
  __syncthreads();
  int n = nlist_s;
  float inv = 1.0f / (float)(n > 1 ? n : 1);
  float a0 = 0.f, a1 = 0.f, a2 = 0.f;
  for (int i = 0; i < n; ++i) {
    const float* r = hs + (size_t)(b * LL + list[i]) * HH;
    a0 += r[t]; a1 += r[t + 256]; a2 += r[t + 512];
  }
  float* dst = hbar + (size_t)(b * MM + m) * HH;
  dst[t] = a0 * inv; dst[t + 256] = a1 * inv; dst[t + 512] = a2 * inv;
}

// ---------------------------------------------------------------- shared GEMM body
// As: A fp32 staged in LDS (cvt_pk->bf16 at frag read), Bs: bf16 N-major.
#define Bb_M 128
#define Bb_N 128
#define Bb_K 64
#define NTK 12

struct GemmAcc { f32x4 acc[4][4]; };

__device__ __forceinline__ void gemm_body(
    float (*As)[Bb_K], short (*Bs)[Bb_K],
    const float* A, const short* Bt, int m0, int n0, int lda_k,
    GemmAcc& g, int t) {
  int lane = t & 63;
  int w = t >> 6;
  int wm = w >> 1, wn = w & 1;

  auto stage = [&](int kt) {
    const float* Ag = A + (size_t)m0 * lda_k + kt * Bb_K;
    const short* Bg = Bt + (size_t)n0 * lda_k + kt * Bb_K;
#pragma unroll
    for (int i = 0; i < 8; ++i) {   // A: 128 rows x 16 chunks of 16B
      int slot = i * 256 + w * 64 + lane;
      int row = slot >> 4, c = slot & 15;
      GLOAD_LDS16(Ag + (size_t)row * lda_k + c * 4,
                  (char*)As + (size_t)(i * 256 + w * 64) * 16);
    }
#pragma unroll
    for (int i = 0; i < 4; ++i) {   // B: 128 rows x 8 chunks of 16B
      int slot = i * 256 + w * 64 + lane;
      int row = slot >> 3, c = slot & 7;
      GLOAD_LDS16(Bg + (size_t)row * lda_k + c * 8,
                  (char*)Bs + (size_t)(i * 256 + w * 64) * 16);
    }
  };

  auto cvt8 = [&](float4 x0, float4 x1) -> s16x8 {
    union { unsigned u[4]; s16x8 v; } r;
    asm("v_cvt_pk_bf16_f32 %0, %1, %2" : "=v"(r.u[0]) : "v"(x0.x), "v"(x0.y));
    asm("v_cvt_pk_bf16_f32 %0, %1, %2" : "=v"(r.u[1]) : "v"(x0.z), "v"(x0.w));
    asm("v_cvt_pk_bf16_f32 %0, %1, %2" : "=v"(r.u[2]) : "v"(x1.x), "v"(x1.y));
    asm("v_cvt_pk_bf16_f32 %0, %1, %2" : "=v"(r.u[3]) : "v"(x1.z), "v"(x1.w));
    return r.v;
  };

  auto compute = [&]() {
#pragma unroll
    for (int kk = 0; kk < 2; ++kk) {
      s16x8 a[4], bb[4];
#pragma unroll
      for (int i = 0; i < 4; ++i) {
        int row = wm * 64 + i * 16 + (lane & 15);
        int k0 = kk * 32 + (lane >> 4) * 8;
        float4 x0 = *(const float4*)&As[row][k0];
        float4 x1 = *(const float4*)&As[row][k0 + 4];
        a[i] = cvt8(x0, x1);
      }
#pragma unroll
      for (int i = 0; i < 4; ++i) {
        int row = wn * 64 + i * 16 + (lane & 15);
        bb[i] = *(const s16x8*)&Bs[row][kk * 32 + (lane >> 4) * 8];
      }
#pragma unroll
      for (int mi = 0; mi < 4; ++mi)
#pragma unroll
        for (int ni = 0; ni < 4; ++ni)
          g.acc[mi][ni] = __builtin_amdgcn_mfma_f32_16x16x32_bf16(a[mi], bb[ni], g.acc[mi][ni], 0, 0, 0);
    }
  };

  for (int kt = 0; kt < NTK; ++kt) {
    stage(kt);
    __syncthreads();
    compute();
    __syncthreads();
  }
}

// ---------------------------------------------------------------- proj_text GEMM (bf16 out)
__global__ __launch_bounds__(256, 3)
void k_gemm_pt(const float* __restrict__ A, const short* __restrict__ Bt,
               const float* __restrict__ bias, short* __restrict__ C) {
  __shared__ float As[Bb_M][Bb_K];   // 32 KB
  __shared__ short Bs[Bb_M][Bb_K];   // 16 KB
  int t = threadIdx.x;
  int lane = t & 63;
  int w = t >> 6;
  int wm = w >> 1, wn = w & 1;
  // XCD-affinity remap: 6 N-tiles of one M-panel land on the same XCD
  int id = blockIdx.x;
  int xcd = id & 7, q = id >> 3;
  int m0 = ((q / 6) * 8 + xcd) * Bb_M;
  int n0 = (q % 6) * Bb_N;

  GemmAcc g = {};
  gemm_body(As, Bs, A, Bt, m0, n0, HH, g, t);

#pragma unroll
  for (int mi = 0; mi < 4; ++mi) {
    int row = m0 + wm * 64 + mi * 16 + ((lane >> 4) * 4);
#pragma unroll
    for (int ni = 0; ni < 4; ++ni) {
      int col = n0 + wn * 64 + ni * 16 + (lane & 15);
      float bv = bias[col];
#pragma unroll
      for (int j = 0; j < 4; ++j)
        C[(size_t)(row + j) * DD + col] = f2bf(g.acc[mi][ni][j] + bv);
    }
  }
}

// ---------------------------------------------------------------- agg = hbar @ Wl^T + bl (fp32 out)
__global__ __launch_bounds__(256, 3)
void k_gemm_agg(const float* __restrict__ hbar, const short* __restrict__ Wlt,
                const float* __restrict__ bl, float* __restrict__ out) {
  __shared__ float As[Bb_M][Bb_K];
  __shared__ short Bs[Bb_M][Bb_K];
  int t = threadIdx.x;
  int lane = t & 63;
  int w = t >> 6;
  int wm = w >> 1, wn = w & 1;
  int n0 = blockIdx.x * Bb_N;   // 6 blocks, m0 = 0

  GemmAcc g = {};
  gemm_body(As, Bs, hbar, Wlt, 0, n0, HH, g, t);

#pragma unroll
  for (int mi = 0; mi < 4; ++mi) {
    int row = wm * 64 + mi * 16 + ((lane >> 4) * 4);
#pragma unroll
    for (int ni = 0; ni < 4; ++ni) {
      int col = n0 + wn * 64 + ni * 16 + (lane & 15);
      float bv = bl[col];
#pragma unroll
      for (int j = 0; j < 4; ++j)
        out[O_AGGL + (size_t)(row + j) * DD + col] = g.acc[mi][ni][j] + bv;
    }
  }
}

// ---------------------------------------------------------------- scores = agg . pt / temp (masked)
__global__ void k_scores(const short* __restrict__ pt, const float* __restrict__ outbuf,
                         const int* __restrict__ lmask, const int* __restrict__ amask,
                         const float* __restrict__ temp_p, float* __restrict__ scores) {
  int chunk = blockIdx.x;
  int b = blockIdx.y;
  int t = threadIdx.x;
  int w = t >> 6, lane = t & 63;
  __shared__ float agg[MM][HH];
  const float* asrc = outbuf + O_AGGL + (size_t)b * MM * DD;
  for (int i = t; i < MM * HH / 4; i += 256)
    *(float4*)&agg[0][i * 4] = *(const float4*)&asrc[i * 4];
  __syncthreads();
  float inv_temp = 1.0f / fmaxf(fabsf(temp_p[0]), 0.1f);
  for (int i = 0; i < 32; ++i) {
    int l = chunk * 128 + w * 32 + i;
    int is_text = (lmask[b * LL + l] == 0) && (amask[b * LL + l] == 1);
    float acc8[8] = {};
    if (is_text) {
      const short* prow = pt + (size_t)(b * LL + l) * DD;
#pragma unroll
      for (int c = 0; c < 3; ++c) {
        s16x4 pv = *(const s16x4*)&prow[c * 256 + lane * 4];
        float p0 = bf2f(pv[0]), p1 = bf2f(pv[1]), p2 = bf2f(pv[2]), p3 = bf2f(pv[3]);
#pragma unroll
        for (int m = 0; m < 8; ++m) {
          float4 av = *(const float4*)&agg[m][c * 256 + lane * 4];
          acc8[m] += p0 * av.x + p1 * av.y + p2 * av.z + p3 * av.w;
        }
      }
#pragma unroll
      for (int m = 0; m < 8; ++m) {
        float v = acc8[m];
        for (int s = 32; s; s >>= 1) v += __shfl_xor(v, s, 64);
        acc8[m] = v;
      }
    }
    if (lane == 0) {
#pragma unroll
      for (int m = 0; m < 8; ++m)
        scores[(size_t)(b * MM + m) * LL + l] = is_text ? acc8[m] * inv_temp : -1e30f;
    }
  }
}

// ---------------------------------------------------------------- row softmax (in place)
__global__ void k_softmax(float* __restrict__ scores) {
  int row = blockIdx.x;
  float* s = scores + (size_t)row * LL;
  int t = threadIdx.x;
  int w = t >> 6, lane = t & 63;
  float v[8];
  float mx = -1e30f;
#pragma unroll
  for (int i = 0; i < 8; ++i) { v[i] = s[t + 256 * i]; mx = fmaxf(mx, v[i]); }
  for (int sh = 32; sh; sh >>= 1) mx = fmaxf(mx, __shfl_xor(mx, sh, 64));
  __shared__ float wred[4];
  __shared__ float wsum[4];
  if (lane == 0) wred[w] = mx;
  __syncthreads();
  mx = fmaxf(fmaxf(wred[0], wred[1]), fmaxf(wred[2], wred[3]));
  float sum = 0.f;
#pragma unroll
  for (int i = 0; i < 8; ++i) { v[i] = __expf(v[i] - mx); sum += v[i]; }
  for (int sh = 32; sh; sh >>= 1) sum += __shfl_xor(sum, sh, 64);
  if (lane == 0) wsum[w] = sum;
  __syncthreads();
  sum = wsum[0] + wsum[1] + wsum[2] + wsum[3];
  float inv = 1.0f / sum;
#pragma unroll
  for (int i = 0; i < 8; ++i) s[t + 256 * i] = v[i] * inv;
}

// ---------------------------------------------------------------- aggregated_text partials
__global__ void k_aggtext_part(const short* __restrict__ pt, const float* __restrict__ attn,
                               float* __restrict__ part) {
  int lc = blockIdx.x;
  int dt = blockIdx.y;
  int b  = blockIdx.z;
  int t = threadIdx.x;
  int m  = t >> 5;
  int c4 = t & 31;
  __shared__ float at_l[MM][256];
  for (int i = t; i < MM * 256; i += 256) {
    int mm = i >> 8, ll = i & 255;
    at_l[mm][ll] = attn[(size_t)(b * MM + mm) * LL + lc * 256 + ll];
  }
  __syncthreads();
  float ax = 0.f, ay = 0.f, az = 0.f, aw = 0.f;
  const short* p = pt + (size_t)(b * LL + lc * 256) * DD + dt * 128 + c4 * 4;
#pragma unroll 4
  for (int ll = 0; ll < 256; ++ll) {
    s16x4 pv = *(const s16x4*)(p + (size_t)ll * DD);
    float a = at_l[m][ll];
    ax += a * bf2f(pv[0]); ay += a * bf2f(pv[1]);
    az += a * bf2f(pv[2]); aw += a * bf2f(pv[3]);
  }
  float* dst = part + ((size_t)(lc * BB + b) * MM + m) * DD + dt * 128 + c4 * 4;
  float4 acc = {ax, ay, az, aw};
  *(float4*)dst = acc;
}

// ---------------------------------------------------------------- reduce partials + cosine head
__global__ void k_head(const float* __restrict__ part, const float* __restrict__ lscale_p,
                       float* __restrict__ out) {
  int row = blockIdx.x;
  int lane = threadIdx.x;
  int b = row >> 3, m = row & 7;
  const float* al = out + O_AGGL + (size_t)row * DD;
  float* at_out = out + O_AGGT + (size_t)row * DD;
  float dot = 0.f, nt = 0.f, nl = 0.f;
  for (int i = lane; i < DD; i += 64) {
    float a = 0.f;
#pragma unroll
    for (int lc = 0; lc < 8; ++lc)
      a += part[((size_t)(lc * BB + b) * MM + m) * DD + i];
    float c = al[i];
    at_out[i] = a;
    dot += a * c; nt += a * a; nl += c * c;
  }
  for (int s = 32; s; s >>= 1) {
    dot += __shfl_xor(dot, s, 64);
    nt  += __shfl_xor(nt, s, 64);
    nl  += __shfl_xor(nl, s, 64);
  }
  if (lane == 0) {
    float scale = expf(lscale_p[0]);
    float denom = fmaxf(sqrtf(nt), 1e-8f) * fmaxf(sqrtf(nl), 1e-8f);
    out[O_LOGITS + row] = dot / denom * scale;
    out[O_BID + row] = (float)(row >> 3);
    out[O_LID + row] = (float)((row & 7) + 1);
    if (row == 0) out[O_SCALE] = scale;
  }
}

extern "C" void kernel_launch(void* const* d_in, const int* in_sizes, int n_in,
                              void* d_out, int out_size, void* d_ws, size_t ws_size,
                              hipStream_t stream) {
  const float* hs    = (const float*)d_in[0];
  const float* Wt    = (const float*)d_in[1];
  const float* bt    = (const float*)d_in[2];
  const float* Wl    = (const float*)d_in[3];
  const float* bl    = (const float*)d_in[4];
  const float* atemp = (const float*)d_in[5];
  const float* lsc   = (const float*)d_in[6];
  const int*   lmask = (const int*)d_in[7];
  const int*   amask = (const int*)d_in[9];
  float* out = (float*)d_out;
  char* ws = (char*)d_ws;
  short* Wtt    = (short*)(ws + WTT_OFF);
  short* pt     = (short*)(ws + PT_OFF);
  float* scores = (float*)(ws + SC_OFF);
  float* part   = (float*)(ws + PART_OFF);
  short* Wlt    = (short*)(ws + WLT_OFF);
  float* hbar   = (float*)(ws + HBAR_OFF);

  k_wt_transpose<<<dim3(12, 12, 2), 256, 0, stream>>>(Wt, Wl, Wtt, Wlt);
  k_hbar<<<128, 256, 0, stream>>>(hs, lmask, hbar);
  k_gemm_agg<<<6, 256, 0, stream>>>(hbar, Wlt, bl, out);
  k_gemm_pt<<<1536, 256, 0, stream>>>(hs, Wtt, bt, pt);
  k_scores<<<dim3(16, 16), 256, 0, stream>>>(pt, out, lmask, amask, atemp, scores);
  k_softmax<<<128, 256, 0, stream>>>(scores);
  k_aggtext_part<<<dim3(8, 6, 16), 256, 0, stream>>>(pt, scores, part);
  k_head<<<128, 64, 0, stream>>>(part, lsc, out);
}

// Round 5
// 188.246 us; speedup vs baseline: 2.4436x; 1.2583x over previous
//
#include <hip/hip_runtime.h>
#include <hip/hip_bf16.h>

typedef __attribute__((ext_vector_type(8))) short s16x8;
typedef __attribute__((ext_vector_type(4))) short s16x4;
typedef __attribute__((ext_vector_type(2))) short s16x2;
typedef __attribute__((ext_vector_type(4))) float f32x4;

#define BB 16
#define LL 2048
#define HH 768
#define DD 768
#define MM 8

// d_out layout (float elements)
#define O_LOGITS 0
#define O_BID    128
#define O_LID    256
#define O_AGGL   384
#define O_SCALE  98688
#define O_AGGT   98689

// ws layout (bytes)
#define WTT_OFF  0u            // 768*768 bf16 = 1179648
#define PT_OFF   1179648u      // 32768*768 bf16 = 50331648
#define SC_OFF   51511296u     // 16*8*2048 fp32 = 1048576
#define PART_OFF 52559872u     // 8*128*768 fp32 = 3145728
#define WLT_OFF  55705600u     // 768*768 bf16 = 1179648
#define HBAR_OFF 56885248u     // 128*768 fp32 = 393216

__device__ __forceinline__ short f2bf(float x) {
  union { float f; unsigned u; } v; v.f = x;
  unsigned r = v.u + 0x7FFFu + ((v.u >> 16) & 1u);
  return (short)(r >> 16);
}
__device__ __forceinline__ float bf2f(short x) {
  union { unsigned u; float f; } v; v.u = ((unsigned)(unsigned short)x) << 16;
  return v.f;
}

// async global->LDS, 16B per lane; LDS dest is wave-uniform base (HW adds lane*16)
#define GLOAD_LDS16(gp, lp) __builtin_amdgcn_global_load_lds( \
    (const __attribute__((address_space(1))) unsigned int*)(gp), \
    (__attribute__((address_space(3))) unsigned int*)(lp), 16, 0, 0)

// ---------------------------------------------------------------- W -> W^T bf16 (Wt and Wl)
__global__ void k_wt_transpose(const float* __restrict__ Wt, const float* __restrict__ Wl,
                               short* __restrict__ Wtt, short* __restrict__ Wlt) {
  __shared__ float tile[64][65];
  const float* src = blockIdx.z ? Wl : Wt;
  short* dst = blockIdx.z ? Wlt : Wtt;
  int kb = blockIdx.x * 64;
  int nb = blockIdx.y * 64;
  int t = threadIdx.x;
  int c = t & 63;
  int r0 = (t >> 6) * 16;
#pragma unroll
  for (int i = 0; i < 16; ++i)
    tile[r0 + i][c] = src[(size_t)(kb + r0 + i) * DD + nb + c];
  __syncthreads();
#pragma unroll
  for (int i = 0; i < 16; ++i)
    dst[(size_t)(nb + r0 + i) * HH + kb + c] = f2bf(tile[c][r0 + i]);
}

// ---------------------------------------------------------------- hbar = segment-mean of hs
__global__ void k_hbar(const float* __restrict__ hs, const int* __restrict__ lmask,
                       float* __restrict__ hbar) {
  int b = blockIdx.x >> 3, m = blockIdx.x & 7;
  int t = threadIdx.x;
  int lane = t & 63, w = t >> 6;
  __shared__ int list[LL];
  __shared__ int nlist_s;
  if (w == 0) {  // deterministic compaction of matching token indices
    int base = 0;
    for (int win = 0; win < LL / 64; ++win) {
      int l = win * 64 + lane;
      bool match = (lmask[b * LL + l] == m + 1);
      unsigned long long mk = __ballot(match);
      if (match) {
        int pos = base + (int)__popcll(mk & ((1ull << lane) - 1ull));
        list[pos] = l;
      }
      base += (int)__popcll(mk);
    }
    if (lane == 0) nlist_s = base;
  }
  __syncthreads();
  int n = nlist_s;
  float inv = 1.0f / (float)(n > 1 ? n : 1);
  float a0 = 0.f, a1 = 0.f, a2 = 0.f;
  for (int i = 0; i < n; ++i) {
    const float* r = hs + (size_t)(b * LL + list[i]) * HH;
    a0 += r[t]; a1 += r[t + 256]; a2 += r[t + 512];
  }
  float* dst = hbar + (size_t)(b * MM + m) * HH;
  dst[t] = a0 * inv; dst[t + 256] = a1 * inv; dst[t + 512] = a2 * inv;
}

// ---------------------------------------------------------------- shared GEMM body
// A fp32 staged in LDS (cvt_pk->bf16 at frag read), B bf16 N-major.
// T2-style XOR swizzle with linear gload_lds dest: physical 16B chunk c of row r
// holds logical chunk c ^ (r&7) (inverse-swizzled global source, swizzled read).
#define Bb_M 128
#define Bb_N 128
#define Bb_K 64
#define NTK 12

struct GemmAcc { f32x4 acc[4][4]; };

__device__ __forceinline__ void gemm_body(
    float (*As)[Bb_K], short (*Bs)[Bb_K],
    const float* A, const short* Bt, int m0, int n0, int lda_k,
    GemmAcc& g, int t) {
  int lane = t & 63;
  int w = t >> 6;
  int wm = w >> 1, wn = w & 1;

  auto stage = [&](int kt) {
    const float* Ag = A + (size_t)m0 * lda_k + kt * Bb_K;
    const short* Bg = Bt + (size_t)n0 * lda_k + kt * Bb_K;
#pragma unroll
    for (int i = 0; i < 8; ++i) {   // A: 128 rows x 16 chunks of 16B
      int slot = i * 256 + w * 64 + lane;
      int row = slot >> 4, c = slot & 15;
      int cs = c ^ (row & 7);       // logical chunk feeding this physical slot
      GLOAD_LDS16(Ag + (size_t)row * lda_k + cs * 4,
                  (char*)As + (size_t)(i * 256 + w * 64) * 16);
    }
#pragma unroll
    for (int i = 0; i < 4; ++i) {   // B: 128 rows x 8 chunks of 16B
      int slot = i * 256 + w * 64 + lane;
      int row = slot >> 3, c = slot & 7;
      int cs = c ^ (row & 7);
      GLOAD_LDS16(Bg + (size_t)row * lda_k + cs * 8,
                  (char*)Bs + (size_t)(i * 256 + w * 64) * 16);
    }
  };

  auto cvt8 = [&](float4 x0, float4 x1) -> s16x8 {
    union { unsigned u[4]; s16x8 v; } r;
    asm("v_cvt_pk_bf16_f32 %0, %1, %2" : "=v"(r.u[0]) : "v"(x0.x), "v"(x0.y));
    asm("v_cvt_pk_bf16_f32 %0, %1, %2" : "=v"(r.u[1]) : "v"(x0.z), "v"(x0.w));
    asm("v_cvt_pk_bf16_f32 %0, %1, %2" : "=v"(r.u[2]) : "v"(x1.x), "v"(x1.y));
    asm("v_cvt_pk_bf16_f32 %0, %1, %2" : "=v"(r.u[3]) : "v"(x1.z), "v"(x1.w));
    return r.v;
  };

  auto compute = [&]() {
#pragma unroll
    for (int kk = 0; kk < 2; ++kk) {
      s16x8 a[4], bb[4];
#pragma unroll
      for (int i = 0; i < 4; ++i) {
        int row = wm * 64 + i * 16 + (lane & 15);
        int c0 = kk * 8 + (lane >> 4) * 2;          // logical 16B chunk (4 floats)
        int p0 = c0 ^ (row & 7), p1 = (c0 + 1) ^ (row & 7);
        float4 x0 = *(const float4*)((const char*)As + (size_t)row * 256 + p0 * 16);
        float4 x1 = *(const float4*)((const char*)As + (size_t)row * 256 + p1 * 16);
        a[i] = cvt8(x0, x1);
      }
#pragma unroll
      for (int i = 0; i < 4; ++i) {
        int row = wn * 64 + i * 16 + (lane & 15);
        int c8 = kk * 4 + (lane >> 4);              // logical 16B chunk (8 bf16)
        int p = c8 ^ (row & 7);
        bb[i] = *(const s16x8*)((const char*)Bs + (size_t)row * 128 + p * 16);
      }
#pragma unroll
      for (int mi = 0; mi < 4; ++mi)
#pragma unroll
        for (int ni = 0; ni < 4; ++ni)
          g.acc[mi][ni] = __builtin_amdgcn_mfma_f32_16x16x32_bf16(a[mi], bb[ni], g.acc[mi][ni], 0, 0, 0);
    }
  };

  for (int kt = 0; kt < NTK; ++kt) {
    stage(kt);
    __syncthreads();
    compute();
    __syncthreads();
  }
}

// ---------------------------------------------------------------- proj_text GEMM (bf16 out)
__global__ __launch_bounds__(256, 3)
void k_gemm_pt(const float* __restrict__ A, const short* __restrict__ Bt,
               const float* __restrict__ bias, short* __restrict__ C) {
  __shared__ float As[Bb_M][Bb_K];   // 32 KB
  __shared__ short Bs[Bb_M][Bb_K];   // 16 KB
  int t = threadIdx.x;
  int lane = t & 63;
  int w = t >> 6;
  int wm = w >> 1, wn = w & 1;
  // XCD-affinity remap: 6 N-tiles of one M-panel land on the same XCD
  int id = blockIdx.x;
  int xcd = id & 7, q = id >> 3;
  int m0 = ((q / 6) * 8 + xcd) * Bb_M;
  int n0 = (q % 6) * Bb_N;

  GemmAcc g = {};
  gemm_body(As, Bs, A, Bt, m0, n0, HH, g, t);

#pragma unroll
  for (int mi = 0; mi < 4; ++mi) {
    int row = m0 + wm * 64 + mi * 16 + ((lane >> 4) * 4);
#pragma unroll
    for (int ni = 0; ni < 4; ++ni) {
      int col = n0 + wn * 64 + ni * 16 + (lane & 15);
      float bv = bias[col];
#pragma unroll
      for (int j = 0; j < 4; ++j)
        C[(size_t)(row + j) * DD + col] = f2bf(g.acc[mi][ni][j] + bv);
    }
  }
}

// ---------------------------------------------------------------- agg = hbar @ Wl^T + bl (fp32 out)
__global__ __launch_bounds__(256, 3)
void k_gemm_agg(const float* __restrict__ hbar, const short* __restrict__ Wlt,
                const float* __restrict__ bl, float* __restrict__ out) {
  __shared__ float As[Bb_M][Bb_K];
  __shared__ short Bs[Bb_M][Bb_K];
  int t = threadIdx.x;
  int lane = t & 63;
  int w = t >> 6;
  int wm = w >> 1, wn = w & 1;
  int n0 = blockIdx.x * Bb_N;   // 6 blocks, m0 = 0

  GemmAcc g = {};
  gemm_body(As, Bs, hbar, Wlt, 0, n0, HH, g, t);

#pragma unroll
  for (int mi = 0; mi < 4; ++mi) {
    int row = wm * 64 + mi * 16 + ((lane >> 4) * 4);
#pragma unroll
    for (int ni = 0; ni < 4; ++ni) {
      int col = n0 + wn * 64 + ni * 16 + (lane & 15);
      float bv = bl[col];
#pragma unroll
      for (int j = 0; j < 4; ++j)
        out[O_AGGL + (size_t)(row + j) * DD + col] = g.acc[mi][ni][j] + bv;
    }
  }
}

// ---------------------------------------------------------------- scores = agg . pt / temp (masked)
__global__ void k_scores(const short* __restrict__ pt, const float* __restrict__ outbuf,
                         const int* __restrict__ lmask, const int* __restrict__ amask,
                         const float* __restrict__ temp_p, float* __restrict__ scores) {
  int chunk = blockIdx.x;
  int b = blockIdx.y;
  int t = threadIdx.x;
  int w = t >> 6, lane = t & 63;
  __shared__ float agg[MM][HH];
  const float* asrc = outbuf + O_AGGL + (size_t)b * MM * DD;
  for (int i = t; i < MM * HH / 4; i += 256)
    *(float4*)&agg[0][i * 4] = *(const float4*)&asrc[i * 4];
  __syncthreads();
  float inv_temp = 1.0f / fmaxf(fabsf(temp_p[0]), 0.1f);
  for (int i = 0; i < 32; ++i) {
    int l = chunk * 128 + w * 32 + i;
    int is_text = (lmask[b * LL + l] == 0) && (amask[b * LL + l] == 1);
    float acc8[8] = {};
    if (is_text) {
      const short* prow = pt + (size_t)(b * LL + l) * DD;
#pragma unroll
      for (int c = 0; c < 3; ++c) {
        s16x4 pv = *(const s16x4*)&prow[c * 256 + lane * 4];
        float p0 = bf2f(pv[0]), p1 = bf2f(pv[1]), p2 = bf2f(pv[2]), p3 = bf2f(pv[3]);
#pragma unroll
        for (int m = 0; m < 8; ++m) {
          float4 av = *(const float4*)&agg[m][c * 256 + lane * 4];
          acc8[m] += p0 * av.x + p1 * av.y + p2 * av.z + p3 * av.w;
        }
      }
#pragma unroll
      for (int m = 0; m < 8; ++m) {
        float v = acc8[m];
        for (int s = 32; s; s >>= 1) v += __shfl_xor(v, s, 64);
        acc8[m] = v;
      }
    }
    if (lane == 0) {
#pragma unroll
      for (int m = 0; m < 8; ++m)
        scores[(size_t)(b * MM + m) * LL + l] = is_text ? acc8[m] * inv_temp : -1e30f;
    }
  }
}

// ---------------------------------------------------------------- row softmax (in place)
__global__ void k_softmax(float* __restrict__ scores) {
  int row = blockIdx.x;
  float* s = scores + (size_t)row * LL;
  int t = threadIdx.x;
  int w = t >> 6, lane = t & 63;
  float v[8];
  float mx = -1e30f;
#pragma unroll
  for (int i = 0; i < 8; ++i) { v[i] = s[t + 256 * i]; mx = fmaxf(mx, v[i]); }
  for (int sh = 32; sh; sh >>= 1) mx = fmaxf(mx, __shfl_xor(mx, sh, 64));
  __shared__ float wred[4];
  __shared__ float wsum[4];
  if (lane == 0) wred[w] = mx;
  __syncthreads();
  mx = fmaxf(fmaxf(wred[0], wred[1]), fmaxf(wred[2], wred[3]));
  float sum = 0.f;
#pragma unroll
  for (int i = 0; i < 8; ++i) { v[i] = __expf(v[i] - mx); sum += v[i]; }
  for (int sh = 32; sh; sh >>= 1) sum += __shfl_xor(sum, sh, 64);
  if (lane == 0) wsum[w] = sum;
  __syncthreads();
  sum = wsum[0] + wsum[1] + wsum[2] + wsum[3];
  float inv = 1.0f / sum;
#pragma unroll
  for (int i = 0; i < 8; ++i) s[t + 256 * i] = v[i] * inv;
}

// ---------------------------------------------------------------- aggregated_text partials
__global__ void k_aggtext_part(const short* __restrict__ pt, const float* __restrict__ attn,
                               float* __restrict__ part) {
  int lc = blockIdx.x;
  int dt = blockIdx.y;
  int b  = blockIdx.z;
  int t = threadIdx.x;
  int m  = t >> 5;
  int c4 = t & 31;
  __shared__ float at_l[MM][256];
  for (int i = t; i < MM * 256; i += 256) {
    int mm = i >> 8, ll = i & 255;
    at_l[mm][ll] = attn[(size_t)(b * MM + mm) * LL + lc * 256 + ll];
  }
  __syncthreads();
  float ax = 0.f, ay = 0.f, az = 0.f, aw = 0.f;
  const short* p = pt + (size_t)(b * LL + lc * 256) * DD + dt * 128 + c4 * 4;
#pragma unroll 4
  for (int ll = 0; ll < 256; ++ll) {
    s16x4 pv = *(const s16x4*)(p + (size_t)ll * DD);
    float a = at_l[m][ll];
    ax += a * bf2f(pv[0]); ay += a * bf2f(pv[1]);
    az += a * bf2f(pv[2]); aw += a * bf2f(pv[3]);
  }
  float* dst = part + ((size_t)(lc * BB + b) * MM + m) * DD + dt * 128 + c4 * 4;
  float4 acc = {ax, ay, az, aw};
  *(float4*)dst = acc;
}

// ---------------------------------------------------------------- reduce partials + cosine head
__global__ void k_head(const float* __restrict__ part, const float* __restrict__ lscale_p,
                       float* __restrict__ out) {
  int row = blockIdx.x;
  int lane = threadIdx.x;
  int b = row >> 3, m = row & 7;
  const float* al = out + O_AGGL + (size_t)row * DD;
  float* at_out = out + O_AGGT + (size_t)row * DD;
  float dot = 0.f, nt = 0.f, nl = 0.f;
  for (int i = lane; i < DD; i += 64) {
    float a = 0.f;
#pragma unroll
    for (int lc = 0; lc < 8; ++lc)
      a += part[((size_t)(lc * BB + b) * MM + m) * DD + i];
    float c = al[i];
    at_out[i] = a;
    dot += a * c; nt += a * a; nl += c * c;
  }
  for (int s = 32; s; s >>= 1) {
    dot += __shfl_xor(dot, s, 64);
    nt  += __shfl_xor(nt, s, 64);
    nl  += __shfl_xor(nl, s, 64);
  }
  if (lane == 0) {
    float scale = expf(lscale_p[0]);
    float denom = fmaxf(sqrtf(nt), 1e-8f) * fmaxf(sqrtf(nl), 1e-8f);
    out[O_LOGITS + row] = dot / denom * scale;
    out[O_BID + row] = (float)(row >> 3);
    out[O_LID + row] = (float)((row & 7) + 1);
    if (row == 0) out[O_SCALE] = scale;
  }
}

extern "C" void kernel_launch(void* const* d_in, const int* in_sizes, int n_in,
                              void* d_out, int out_size, void* d_ws, size_t ws_size,
                              hipStream_t stream) {
  const float* hs    = (const float*)d_in[0];
  const float* Wt    = (const float*)d_in[1];
  const float* bt    = (const float*)d_in[2];
  const float* Wl    = (const float*)d_in[3];
  const float* bl    = (const float*)d_in[4];
  const float* atemp = (const float*)d_in[5];
  const float* lsc   = (const float*)d_in[6];
  const int*   lmask = (const int*)d_in[7];
  const int*   amask = (const int*)d_in[9];
  float* out = (float*)d_out;
  char* ws = (char*)d_ws;
  short* Wtt    = (short*)(ws + WTT_OFF);
  short* pt     = (short*)(ws + PT_OFF);
  float* scores = (float*)(ws + SC_OFF);
  float* part   = (float*)(ws + PART_OFF);
  short* Wlt    = (short*)(ws + WLT_OFF);
  float* hbar   = (float*)(ws + HBAR_OFF);

  k_wt_transpose<<<dim3(12, 12, 2), 256, 0, stream>>>(Wt, Wl, Wtt, Wlt);
  k_hbar<<<128, 256, 0, stream>>>(hs, lmask, hbar);
  k_gemm_agg<<<6, 256, 0, stream>>>(hbar, Wlt, bl, out);
  k_gemm_pt<<<1536, 256, 0, stream>>>(hs, Wtt, bt, pt);
  k_scores<<<dim3(16, 16), 256, 0, stream>>>(pt, out, lmask, amask, atemp, scores);
  k_softmax<<<128, 256, 0, stream>>>(scores);
  k_aggtext_part<<<dim3(8, 6, 16), 256, 0, stream>>>(pt, scores, part);
  k_head<<<128, 64, 0, stream>>>(part, lsc, out);
}

// Round 6
// 186.088 us; speedup vs baseline: 2.4719x; 1.0116x over previous
//
#include <hip/hip_runtime.h>
#include <hip/hip_bf16.h>

typedef __attribute__((ext_vector_type(8))) short s16x8;
typedef __attribute__((ext_vector_type(4))) short s16x4;
typedef __attribute__((ext_vector_type(2))) short s16x2;
typedef __attribute__((ext_vector_type(4))) float f32x4;

#define BB 16
#define LL 2048
#define HH 768
#define DD 768
#define MM 8

// d_out layout (float elements)
#define O_LOGITS 0
#define O_BID    128
#define O_LID    256
#define O_AGGL   384
#define O_SCALE  98688
#define O_AGGT   98689

// ws layout (bytes)
#define WTT_OFF  0u            // 768*768 bf16 = 1179648
#define PT_OFF   1179648u      // 32768*768 bf16 = 50331648
#define SC_OFF   51511296u     // 16*8*2048 fp32 = 1048576
#define PART_OFF 52559872u     // 8*128*768 fp32 = 3145728
#define WLT_OFF  55705600u     // 768*768 bf16 = 1179648
#define HBAR_OFF 56885248u     // 128*768 fp32 = 393216

__device__ __forceinline__ short f2bf(float x) {
  union { float f; unsigned u; } v; v.f = x;
  unsigned r = v.u + 0x7FFFu + ((v.u >> 16) & 1u);
  return (short)(r >> 16);
}
__device__ __forceinline__ float bf2f(short x) {
  union { unsigned u; float f; } v; v.u = ((unsigned)(unsigned short)x) << 16;
  return v.f;
}

// async global->LDS, 16B per lane; LDS dest is wave-uniform base (HW adds lane*16)
#define GLOAD_LDS16(gp, lp) __builtin_amdgcn_global_load_lds( \
    (const __attribute__((address_space(1))) unsigned int*)(gp), \
    (__attribute__((address_space(3))) unsigned int*)(lp), 16, 0, 0)

// ---------------------------------------------------------------- W -> W^T bf16 (Wt and Wl)
__global__ void k_wt_transpose(const float* __restrict__ Wt, const float* __restrict__ Wl,
                               short* __restrict__ Wtt, short* __restrict__ Wlt) {
  __shared__ float tile[64][65];
  const float* src = blockIdx.z ? Wl : Wt;
  short* dst = blockIdx.z ? Wlt : Wtt;
  int kb = blockIdx.x * 64;
  int nb = blockIdx.y * 64;
  int t = threadIdx.x;
  int c = t & 63;
  int r0 = (t >> 6) * 16;
#pragma unroll
  for (int i = 0; i < 16; ++i)
    tile[r0 + i][c] = src[(size_t)(kb + r0 + i) * DD + nb + c];
  __syncthreads();
#pragma unroll
  for (int i = 0; i < 16; ++i)
    dst[(size_t)(nb + r0 + i) * HH + kb + c] = f2bf(tile[c][r0 + i]);
}

// ---------------------------------------------------------------- hbar = segment-mean of hs
__global__ void k_hbar(const float* __restrict__ hs, const int* __restrict__ lmask,
                       float* __restrict__ hbar) {
  int b = blockIdx.x >> 3, m = blockIdx.x & 7;
  int t = threadIdx.x;
  int lane = t & 63, w = t >> 6;
  __shared__ int list[LL];
  __shared__ int nlist_s;
  if (w == 0) {  // deterministic compaction of matching token indices
    int base = 0;
    for (int win = 0; win < LL / 64; ++win) {
      int l = win * 64 + lane;
      bool match = (lmask[b * LL + l] == m + 1);
      unsigned long long mk = __ballot(match);
      if (match) {
        int pos = base + (int)__popcll(mk & ((1ull << lane) - 1ull));
        list[pos] = l;
      }
      base += (int)__popcll(mk);
    }
    if (lane == 0) nlist_s = base;
  }
  __syncthreads();
  int n = nlist_s;
  float inv = 1.0f / (float)(n > 1 ? n : 1);
  float a0 = 0.f, a1 = 0.f, a2 = 0.f;
  for (int i = 0; i < n; ++i) {
    const float* r = hs + (size_t)(b * LL + list[i]) * HH;
    a0 += r[t]; a1 += r[t + 256]; a2 += r[t + 512];
  }
  float* dst = hbar + (size_t)(b * MM + m) * HH;
  dst[t] = a0 * inv; dst[t + 256] = a1 * inv; dst[t + 512] = a2 * inv;
}

// ---------------------------------------------------------------- shared GEMM body
// A fp32 reg-staged -> cvt_pk -> bf16 LDS (T14 async split: issue loads before
// compute, cvt+ds_write after the post-compute barrier). B bf16 double-buffered
// via global_load_lds. Both LDS tiles are bf16 [128][64] with the 16B-chunk
// XOR swizzle phys = c ^ (row&7) (zero-conflict 128B-row pattern).
#define Bb_M 128
#define Bb_N 128
#define Bb_K 64
#define NTK 12

struct GemmAcc { f32x4 acc[4][4]; };

__device__ __forceinline__ void gemm_body(
    short* AsB, short* BsB,
    const float* A, const short* Bt, int m0, int n0, int lda_k,
    GemmAcc& g, int t) {
  int lane = t & 63;
  int w = t >> 6;
  int wm = w >> 1, wn = w & 1;

  float4 areg[8];

  auto issueA = [&](int kt) {
    const float* Ag = A + (size_t)m0 * lda_k + kt * Bb_K;
#pragma unroll
    for (int i = 0; i < 8; ++i) {
      int slot = i * 256 + t;
      int row = slot >> 4, c = slot & 15;      // 16B fp32 chunk (4 floats)
      areg[i] = *(const float4*)(Ag + (size_t)row * lda_k + c * 4);
    }
  };
  auto issueB = [&](int kt, int buf) {
    const short* Bg = Bt + (size_t)n0 * lda_k + kt * Bb_K;
#pragma unroll
    for (int i = 0; i < 4; ++i) {
      int slot = i * 256 + w * 64 + lane;
      int row = slot >> 3, c = slot & 7;       // 16B bf16 chunk
      int cs = c ^ (row & 7);                  // inverse-swizzled global source
      GLOAD_LDS16(Bg + (size_t)row * lda_k + cs * 8,
                  (char*)BsB + (size_t)buf * 16384 + (size_t)(i * 256 + w * 64) * 16);
    }
  };
  auto writeA = [&]() {   // cvt_pk + swizzled ds_write_b64 (after barrier)
#pragma unroll
    for (int i = 0; i < 8; ++i) {
      int slot = i * 256 + t;
      int row = slot >> 4, c = slot & 15;      // c = 8B-unit index of bf16 row
      unsigned d0, d1;
      asm("v_cvt_pk_bf16_f32 %0, %1, %2" : "=v"(d0) : "v"(areg[i].x), "v"(areg[i].y));
      asm("v_cvt_pk_bf16_f32 %0, %1, %2" : "=v"(d1) : "v"(areg[i].z), "v"(areg[i].w));
      int phys = (c >> 1) ^ (row & 7);
      uint2 val = {d0, d1};
      *(uint2*)((char*)AsB + (size_t)row * 128 + phys * 16 + (c & 1) * 8) = val;
    }
  };
  auto compute = [&](int buf) {
#pragma unroll
    for (int kk = 0; kk < 2; ++kk) {
      s16x8 a[4], bb[4];
#pragma unroll
      for (int i = 0; i < 4; ++i) {
        int row = wm * 64 + i * 16 + (lane & 15);
        int p = (kk * 4 + (lane >> 4)) ^ (row & 7);
        a[i] = *(const s16x8*)((const char*)AsB + (size_t)row * 128 + p * 16);
      }
#pragma unroll
      for (int i = 0; i < 4; ++i) {
        int row = wn * 64 + i * 16 + (lane & 15);
        int p = (kk * 4 + (lane >> 4)) ^ (row & 7);
        bb[i] = *(const s16x8*)((const char*)BsB + (size_t)buf * 16384 + (size_t)row * 128 + p * 16);
      }
#pragma unroll
      for (int mi = 0; mi < 4; ++mi)
#pragma unroll
        for (int ni = 0; ni < 4; ++ni)
          g.acc[mi][ni] = __builtin_amdgcn_mfma_f32_16x16x32_bf16(a[mi], bb[ni], g.acc[mi][ni], 0, 0, 0);
    }
  };

  // prologue
  issueA(0); issueB(0, 0);
  writeA();                 // compiler inserts vmcnt wait for areg uses
  __syncthreads();          // drains B(0) gload + makes As(0) visible
  for (int kt = 0; kt < NTK; ++kt) {
    if (kt + 1 < NTK) { issueA(kt + 1); issueB(kt + 1, (kt + 1) & 1); }
    compute(kt & 1);        // loads for kt+1 in flight during compute
    __syncthreads();        // all waves done reading As / Bs[cur]
    if (kt + 1 < NTK) {
      writeA();             // A(kt+1) -> LDS (regs arrived ~compute ago)
      __syncthreads();      // As(kt+1) + Bs[nxt] ready
    }
  }
}

// ---------------------------------------------------------------- proj_text GEMM (bf16 out)
__global__ __launch_bounds__(256, 3)
void k_gemm_pt(const float* __restrict__ A, const short* __restrict__ Bt,
               const float* __restrict__ bias, short* __restrict__ C) {
  __shared__ short As[Bb_M][Bb_K];        // 16 KB
  __shared__ short Bs[2][Bb_M][Bb_K];     // 32 KB
  int t = threadIdx.x;
  int lane = t & 63;
  int w = t >> 6;
  int wm = w >> 1, wn = w & 1;
  // XCD-affinity remap: 6 N-tiles of one M-panel land on the same XCD
  int id = blockIdx.x;
  int xcd = id & 7, q = id >> 3;
  int m0 = ((q / 6) * 8 + xcd) * Bb_M;
  int n0 = (q % 6) * Bb_N;

  GemmAcc g = {};
  gemm_body(&As[0][0], &Bs[0][0][0], A, Bt, m0, n0, HH, g, t);

#pragma unroll
  for (int mi = 0; mi < 4; ++mi) {
    int row = m0 + wm * 64 + mi * 16 + ((lane >> 4) * 4);
#pragma unroll
    for (int ni = 0; ni < 4; ++ni) {
      int col = n0 + wn * 64 + ni * 16 + (lane & 15);
      float bv = bias[col];
#pragma unroll
      for (int j = 0; j < 4; ++j)
        C[(size_t)(row + j) * DD + col] = f2bf(g.acc[mi][ni][j] + bv);
    }
  }
}

// ---------------------------------------------------------------- agg = hbar @ Wl^T + bl (fp32 out)
__global__ __launch_bounds__(256, 3)
void k_gemm_agg(const float* __restrict__ hbar, const short* __restrict__ Wlt,
                const float* __restrict__ bl, float* __restrict__ out) {
  __shared__ short As[Bb_M][Bb_K];
  __shared__ short Bs[2][Bb_M][Bb_K];
  int t = threadIdx.x;
  int lane = t & 63;
  int w = t >> 6;
  int wm = w >> 1, wn = w & 1;
  int n0 = blockIdx.x * Bb_N;   // 6 blocks, m0 = 0

  GemmAcc g = {};
  gemm_body(&As[0][0], &Bs[0][0][0], hbar, Wlt, 0, n0, HH, g, t);

#pragma unroll
  for (int mi = 0; mi < 4; ++mi) {
    int row = wm * 64 + mi * 16 + ((lane >> 4) * 4);
#pragma unroll
    for (int ni = 0; ni < 4; ++ni) {
      int col = n0 + wn * 64 + ni * 16 + (lane & 15);
      float bv = bl[col];
#pragma unroll
      for (int j = 0; j < 4; ++j)
        out[O_AGGL + (size_t)(row + j) * DD + col] = g.acc[mi][ni][j] + bv;
    }
  }
}

// ---------------------------------------------------------------- scores = agg . pt / temp (masked)
__global__ void k_scores(const short* __restrict__ pt, const float* __restrict__ outbuf,
                         const int* __restrict__ lmask, const int* __restrict__ amask,
                         const float* __restrict__ temp_p, float* __restrict__ scores) {
  int chunk = blockIdx.x;
  int b = blockIdx.y;
  int t = threadIdx.x;
  int w = t >> 6, lane = t & 63;
  __shared__ float agg[MM][HH];
  const float* asrc = outbuf + O_AGGL + (size_t)b * MM * DD;
  for (int i = t; i < MM * HH / 4; i += 256)
    *(float4*)&agg[0][i * 4] = *(const float4*)&asrc[i * 4];
  __syncthreads();
  float inv_temp = 1.0f / fmaxf(fabsf(temp_p[0]), 0.1f);
  for (int i = 0; i < 32; ++i) {
    int l = chunk * 128 + w * 32 + i;
    int is_text = (lmask[b * LL + l] == 0) && (amask[b * LL + l] == 1);
    float acc8[8] = {};
    if (is_text) {
      const short* prow = pt + (size_t)(b * LL + l) * DD;
#pragma unroll
      for (int c = 0; c < 3; ++c) {
        s16x4 pv = *(const s16x4*)&prow[c * 256 + lane * 4];
        float p0 = bf2f(pv[0]), p1 = bf2f(pv[1]), p2 = bf2f(pv[2]), p3 = bf2f(pv[3]);
#pragma unroll
        for (int m = 0; m < 8; ++m) {
          float4 av = *(const float4*)&agg[m][c * 256 + lane * 4];
          acc8[m] += p0 * av.x + p1 * av.y + p2 * av.z + p3 * av.w;
        }
      }
#pragma unroll
      for (int m = 0; m < 8; ++m) {
        float v = acc8[m];
        for (int s = 32; s; s >>= 1) v += __shfl_xor(v, s, 64);
        acc8[m] = v;
      }
    }
    if (lane == 0) {
#pragma unroll
      for (int m = 0; m < 8; ++m)
        scores[(size_t)(b * MM + m) * LL + l] = is_text ? acc8[m] * inv_temp : -1e30f;
    }
  }
}

// ---------------------------------------------------------------- row softmax (in place)
__global__ void k_softmax(float* __restrict__ scores) {
  int row = blockIdx.x;
  float* s = scores + (size_t)row * LL;
  int t = threadIdx.x;
  int w = t >> 6, lane = t & 63;
  float v[8];
  float mx = -1e30f;
#pragma unroll
  for (int i = 0; i < 8; ++i) { v[i] = s[t + 256 * i]; mx = fmaxf(mx, v[i]); }
  for (int sh = 32; sh; sh >>= 1) mx = fmaxf(mx, __shfl_xor(mx, sh, 64));
  __shared__ float wred[4];
  __shared__ float wsum[4];
  if (lane == 0) wred[w] = mx;
  __syncthreads();
  mx = fmaxf(fmaxf(wred[0], wred[1]), fmaxf(wred[2], wred[3]));
  float sum = 0.f;
#pragma unroll
  for (int i = 0; i < 8; ++i) { v[i] = __expf(v[i] - mx); sum += v[i]; }
  for (int sh = 32; sh; sh >>= 1) sum += __shfl_xor(sum, sh, 64);
  if (lane == 0) wsum[w] = sum;
  __syncthreads();
  sum = wsum[0] + wsum[1] + wsum[2] + wsum[3];
  float inv = 1.0f / sum;
#pragma unroll
  for (int i = 0; i < 8; ++i) s[t + 256 * i] = v[i] * inv;
}

// ---------------------------------------------------------------- aggregated_text partials
__global__ void k_aggtext_part(const short* __restrict__ pt, const float* __restrict__ attn,
                               float* __restrict__ part) {
  int lc = blockIdx.x;
  int dt = blockIdx.y;
  int b  = blockIdx.z;
  int t = threadIdx.x;
  int m  = t >> 5;
  int c4 = t & 31;
  __shared__ float at_l[MM][256];
  for (int i = t; i < MM * 256; i += 256) {
    int mm = i >> 8, ll = i & 255;
    at_l[mm][ll] = attn[(size_t)(b * MM + mm) * LL + lc * 256 + ll];
  }
  __syncthreads();
  float ax = 0.f, ay = 0.f, az = 0.f, aw = 0.f;
  const short* p = pt + (size_t)(b * LL + lc * 256) * DD + dt * 128 + c4 * 4;
#pragma unroll 4
  for (int ll = 0; ll < 256; ++ll) {
    s16x4 pv = *(const s16x4*)(p + (size_t)ll * DD);
    float a = at_l[m][ll];
    ax += a * bf2f(pv[0]); ay += a * bf2f(pv[1]);
    az += a * bf2f(pv[2]); aw += a * bf2f(pv[3]);
  }
  float* dst = part + ((size_t)(lc * BB + b) * MM + m) * DD + dt * 128 + c4 * 4;
  float4 acc = {ax, ay, az, aw};
  *(float4*)dst = acc;
}

// ---------------------------------------------------------------- reduce partials + cosine head
__global__ void k_head(const float* __restrict__ part, const float* __restrict__ lscale_p,
                       float* __restrict__ out) {
  int row = blockIdx.x;
  int lane = threadIdx.x;
  int b = row >> 3, m = row & 7;
  const float* al = out + O_AGGL + (size_t)row * DD;
  float* at_out = out + O_AGGT + (size_t)row * DD;
  float dot = 0.f, nt = 0.f, nl = 0.f;
  for (int i = lane; i < DD; i += 64) {
    float a = 0.f;
#pragma unroll
    for (int lc = 0; lc < 8; ++lc)
      a += part[((size_t)(lc * BB + b) * MM + m) * DD + i];
    float c = al[i];
    at_out[i] = a;
    dot += a * c; nt += a * a; nl += c * c;
  }
  for (int s = 32; s; s >>= 1) {
    dot += __shfl_xor(dot, s, 64);
    nt  += __shfl_xor(nt, s, 64);
    nl  += __shfl_xor(nl, s, 64);
  }
  if (lane == 0) {
    float scale = expf(lscale_p[0]);
    float denom = fmaxf(sqrtf(nt), 1e-8f) * fmaxf(sqrtf(nl), 1e-8f);
    out[O_LOGITS + row] = dot / denom * scale;
    out[O_BID + row] = (float)(row >> 3);
    out[O_LID + row] = (float)((row & 7) + 1);
    if (row == 0) out[O_SCALE] = scale;
  }
}

extern "C" void kernel_launch(void* const* d_in, const int* in_sizes, int n_in,
                              void* d_out, int out_size, void* d_ws, size_t ws_size,
                              hipStream_t stream) {
  const float* hs    = (const float*)d_in[0];
  const float* Wt    = (const float*)d_in[1];
  const float* bt    = (const float*)d_in[2];
  const float* Wl    = (const float*)d_in[3];
  const float* bl    = (const float*)d_in[4];
  const float* atemp = (const float*)d_in[5];
  const float* lsc   = (const float*)d_in[6];
  const int*   lmask = (const int*)d_in[7];
  const int*   amask = (const int*)d_in[9];
  float* out = (float*)d_out;
  char* ws = (char*)d_ws;
  short* Wtt    = (short*)(ws + WTT_OFF);
  short* pt     = (short*)(ws + PT_OFF);
  float* scores = (float*)(ws + SC_OFF);
  float* part   = (float*)(ws + PART_OFF);
  short* Wlt    = (short*)(ws + WLT_OFF);
  float* hbar   = (float*)(ws + HBAR_OFF);

  k_wt_transpose<<<dim3(12, 12, 2), 256, 0, stream>>>(Wt, Wl, Wtt, Wlt);
  k_hbar<<<128, 256, 0, stream>>>(hs, lmask, hbar);
  k_gemm_agg<<<6, 256, 0, stream>>>(hbar, Wlt, bl, out);
  k_gemm_pt<<<1536, 256, 0, stream>>>(hs, Wtt, bt, pt);
  k_scores<<<dim3(16, 16), 256, 0, stream>>>(pt, out, lmask, amask, atemp, scores);
  k_softmax<<<128, 256, 0, stream>>>(scores);
  k_aggtext_part<<<dim3(8, 6, 16), 256, 0, stream>>>(pt, scores, part);
  k_head<<<128, 64, 0, stream>>>(part, lsc, out);
}